// Round 4
// baseline (254.237 us; speedup 1.0000x reference)
//
#include <hip/hip_runtime.h>

// RandomlyLocalizedConformalRiskControl on MI355X.
// ws layout (bytes), total ~98.5 MB:
//   test_res f32 [32][65536]             @ 0          (8 MB)    f32 scores for final scan
//   cal_bf   u16 [256][65536]            @ 8388608    (32 MB)   bf16 cal scores (MFMA A/B)
//   test_bf  u16 [32][65536]             @ 41943040   (4 MB)    bf16 test scores
//   grouped  u16 [256][65536]            @ 46137344   (32 MB)   low-16 bits of f32 score, grouped by hi-16 bucket
//   cdf      u32 [256][CDF_STRIDE]       @ 79691776   (16 MB)   exclusive CDF over 16256 hi-16 buckets; [HB]=pos
//   gpart    f32 [64][8][1024]           @ 96354304   (2 MB)    split-K MFMA partials (deterministic)
//   cc f32[256]
// Pipeline fused to 3 kernels (was 6): k_calt -> k_gemm -> k_quantf.
// k_quantf absorbs k_tt (bit-exact virtual-thread replica), k_finalp (integer counts,
// order-invariant) and k_out (direct out writes) — removes 3 launches + facc roundtrip.

#define NPIX 65536
#define HB 16256            // buckets = float_bits >> 16 for scores in (0, 1.0]
#define CDF_STRIDE 16272
#define ALPHA 0.1f
#define STAGE_CAP 40960     // u16 staging entries for the grouped scatter (pos ~ 33K)

#define OFF_TESTRES  0
#define OFF_CALBF    8388608u
#define OFF_TESTBF   41943040u
#define OFF_GROUPED  46137344u
#define OFF_CDF      79691776u
#define OFF_GPART    96354304u
#define OFF_CC       98451456u

typedef __attribute__((ext_vector_type(8))) short bf16x8;
typedef __attribute__((ext_vector_type(16))) float f32x16;

__device__ __forceinline__ unsigned short f2bf_rne(float f) {
  unsigned u = __float_as_uint(f);
  return (unsigned short)((u + 0x7FFFu + ((u >> 16) & 1u)) >> 16);
}

// XOR swizzle on packed-word index: involution, closed within each 32-word block,
// spreads the stride-8 scan access pattern to ~2-way (free) bank aliasing.
__device__ __forceinline__ int SW(int w) { return w ^ ((w >> 5) & 31); }

// Shared helpers: every score evaluation site (test chain, phase-A chain, phase-B
// score_at) funnels through the SAME inlined expression DAG -> identical FMA
// contraction -> bit-identical f32 results on recompute/reuse.
__device__ __forceinline__ float hrow_at(const float* __restrict__ f, int x0, int x1,
                                         float wx, int r) {
  return f[r * 64 + x0] * (1.f - wx) + f[r * 64 + x1] * wx;
}
__device__ __forceinline__ float sig_v(float a, float b, float wy) {
  float v = a * (1.f - wy) + b * wy;
  return 1.f / (1.f + __expf(-v));
}
__device__ __forceinline__ float score_at(const float* __restrict__ sfeat,
                                          int x0, int x1, float wx, int y) {
  float sy = 0.25f * (float)y - 0.375f;
  int y0 = (int)floorf(sy);
  float wy = sy - (float)y0;
  int y1 = y0 + 1;
  if (y0 < 0) y0 = 0;
  if (y1 > 63) y1 = 63;
  float a = hrow_at(sfeat, x0, x1, wx, y0);
  float b = hrow_at(sfeat, x0, x1, wx, y1);
  return sig_v(a, b, wy);
}

// ---- fused cal+test features, 256 blocks (one per cal sample) ----
// Block n: cal sample n (hist + CDF + scatter + bf16 + cc) AND a 1/8 slice of test
// sample n>>3. Row-interp CHAIN: for fixed thread, y=it*4+yq => sy advances by exactly
// 1.0 per it (exact dyadic) => y0 increments by 1, wy is a per-thread constant, and
// b's row-interp at step it IS a's row-interp at it+1 — carried in a register. Halves
// LDS reads and ~25% of VALU in the score loops; bit-exact by construction.
// smem map (u32): [0,8192) packed hist->counters (swizzled); [8192,8208) wave totals;
// [8208,8224) cc partials; [8224,9248) per-thread scan prefixes; [9248] pos.
__global__ __launch_bounds__(1024, 2) void k_calt(const float* __restrict__ featc,
                                                  const int* __restrict__ gt,
                                                  unsigned short* __restrict__ calbf,
                                                  unsigned* __restrict__ cdf,
                                                  unsigned short* __restrict__ grouped,
                                                  float* __restrict__ cc,
                                                  const float* __restrict__ featt,
                                                  float* __restrict__ tres,
                                                  unsigned short* __restrict__ tbf) {
  __shared__ unsigned smem[9264];
  __shared__ float sfeat[4096];
  __shared__ float tfeat[4096];
  __shared__ unsigned short sstage[STAGE_CAP];
  const int tid = threadIdx.x;
  const int lane = tid & 63, wv = tid >> 6;
  const int x = tid & 255, yq = tid >> 8;  // yq in 0..3
  float sx = 0.25f * (float)x - 0.375f;
  int x0 = (int)floorf(sx);
  float wx = sx - (float)x0;
  int x1 = x0 + 1;
  if (x0 < 0) x0 = 0;
  if (x1 > 63) x1 = 63;
  // chain constants (exact dyadic => identical bits to per-call values)
  const float syq = 0.25f * (float)yq - 0.375f;
  const int c0 = (int)floorf(syq);        // -1 for yq<2, 0 for yq>=2
  const float wy = syq - (float)c0;       // constant across it

  const int n = blockIdx.x;
  const int b = n >> 3, sl = n & 7;  // test sample + slice handled by this block
  for (int i = tid; i < 8192; i += 1024) smem[i] = 0;
  for (int i = tid; i < 4096; i += 1024) {
    sfeat[i] = featc[n * 4096 + i];
    tfeat[i] = featt[b * 4096 + i];
  }
  const int* gtn = gt + (size_t)n * NPIX;
  unsigned short* cbn = calbf + (size_t)n * NPIX;
  __syncthreads();  // S0: feats + hist zeroed

  // ---- test slice: pixels [sl*8192, (sl+1)*8192); chain over 8 rows ----
  {
    float* resb = tres + (size_t)b * NPIX + sl * 8192;
    unsigned short* tbn = tbf + (size_t)b * NPIX + sl * 8192;
    int r0 = sl * 8 + c0;
    if (r0 < 0) r0 = 0;
    float hprev = hrow_at(tfeat, x0, x1, wx, r0);
    #pragma unroll
    for (int i = 0; i < 8; ++i) {
      int r1 = sl * 8 + i + c0 + 1;
      if (r1 > 63) r1 = 63;
      float hb = hrow_at(tfeat, x0, x1, wx, r1);
      float s = sig_v(hprev, hb, wy);
      hprev = hb;
      int q = i * 1024 + tid;
      resb[q] = s;
      tbn[q] = f2bf_rne(s);
    }
  }

  // ---- cal phase A: chained scores, bf16 write, packed-hist atomics, cc ----
  unsigned long long pm = 0ull;
  float sumsq = 0.f;
  {
    int r0 = c0 < 0 ? 0 : c0;
    float hprev = hrow_at(sfeat, x0, x1, wx, r0);
    #pragma unroll 8
    for (int it = 0; it < 64; ++it) {
      int r1 = it + c0 + 1;
      if (r1 > 63) r1 = 63;
      float hb = hrow_at(sfeat, x0, x1, wx, r1);
      float s = sig_v(hprev, hb, wy);
      hprev = hb;
      int p = ((it * 4 + yq) << 8) + x;
      unsigned short bh = f2bf_rne(s);
      cbn[p] = bh;
      float sr = __uint_as_float((unsigned)bh << 16);
      sumsq += sr * sr;
      if (gtn[p] > 0) {
        pm |= (1ull << it);
        unsigned bits = __float_as_uint(s);
        atomicAdd(&smem[SW((int)(bits >> 17))], (bits & 0x10000u) ? 0x10000u : 1u);
      }
    }
  }
  // cc partials (16 waves), exact old summation order
  #pragma unroll
  for (int off = 32; off; off >>= 1) sumsq += __shfl_xor(sumsq, off);
  if (lane == 0) smem[8208 + wv] = __float_as_uint(sumsq);
  __syncthreads();  // S1: hist + cc partials final
  if (tid == 0) {
    float c = 0.f;
    for (int w = 0; w < 16; ++w) c += __uint_as_float(smem[8208 + w]);
    cc[n] = c;
  }
  // ---- exclusive scan, all 1024 threads, 8 packed words (16 buckets) each ----
  const int wbase = tid * 8;
  unsigned psum = 0;
  #pragma unroll
  for (int j = 0; j < 8; ++j) {
    unsigned w = smem[SW(wbase + j)];
    psum += (w & 0xFFFFu) + (w >> 16);
  }
  unsigned inc = psum;
  #pragma unroll
  for (int off = 1; off < 64; off <<= 1) {
    unsigned v = __shfl_up(inc, off);
    if (lane >= off) inc += v;
  }
  if (lane == 63) smem[8192 + wv] = inc;  // wave totals
  smem[8224 + tid] = inc - psum;          // thread-exclusive prefix within wave
  __syncthreads();  // S2: totals + prefixes ready
  {
    unsigned woff = 0;
    for (int w = 0; w < wv; ++w) woff += smem[8192 + w];  // broadcast reads
    unsigned run = woff + smem[8224 + tid];
    #pragma unroll
    for (int j = 0; j < 8; ++j) {
      int si = SW(wbase + j);
      unsigned w = smem[si];
      unsigned clo = run;
      run += (w & 0xFFFFu);
      unsigned chi = run;
      run += (w >> 16);
      smem[si] = (chi << 16) | clo;  // packed exclusive CDF -> scatter counters
    }
    if (tid == 1023) smem[9248] = run;  // total positives
  }
  __syncthreads();  // S2b: counters final
  // ---- COALESCED cdf copyout ----
  unsigned* cdfn = cdf + (size_t)n * CDF_STRIDE;
  for (int i = tid; i < HB; i += 1024) {
    unsigned w = smem[SW(i >> 1)];
    cdfn[i] = (i & 1) ? (w >> 16) : (w & 0xFFFFu);
  }
  const unsigned pos = smem[9248];
  if (tid == 0) cdfn[HB] = pos;
  __syncthreads();  // S3: cdf written before counters mutate
  // ---- phase B: recompute scores (bit-exact via shared helpers), LDS staging ----
  unsigned short* gn = grouped + (size_t)n * NPIX;
  for (int it = 0; it < 64; ++it) {
    if (pm & (1ull << it)) {
      int y = it * 4 + yq;
      float s = score_at(sfeat, x0, x1, wx, y);
      unsigned bits = __float_as_uint(s);
      unsigned old = atomicAdd(&smem[SW((int)(bits >> 17))], (bits & 0x10000u) ? 0x10000u : 1u);
      unsigned idx = (bits & 0x10000u) ? (old >> 16) : (old & 0xFFFFu);
      unsigned short lo = (unsigned short)(bits & 0xFFFFu);
      if (idx < STAGE_CAP) sstage[idx] = lo;
      else gn[idx] = lo;  // overflow fallback: same final location, direct store
    }
  }
  __syncthreads();  // S4: staging complete
  // ---- COALESCED grouped copyout ----
  unsigned lim = pos < STAGE_CAP ? pos : STAGE_CAP;
  for (unsigned i = tid; i < lim; i += 1024) gn[i] = sstage[i];
}

// ---- LDS-staged bf16 MFMA GEMM: gpart[ks][nt][m*32+nl] = <test_m, cal_(nt*32+nl)> ----
// Coalesced 1KB/wave global loads into XOR-swizzled [kblk][row][16B] tiles; ds_read_b128
// fragments; wave = K-quarter split, cross-wave reduce in lred. 80 KB LDS -> 2 blocks/CU.
__global__ __launch_bounds__(256) void k_gemm(const unsigned short* __restrict__ tbf,
                                              const unsigned short* __restrict__ cbf,
                                              float* __restrict__ gpart) {
  __shared__ __align__(16) unsigned short As[16384];  // 32 KB: 64 kblk x 32 row x 8 elems
  __shared__ __align__(16) unsigned short Bs[16384];
  __shared__ float lred[4][1024];                     // 16 KB
  const int tid = threadIdx.x;
  const int lane = tid & 63, wv = tid >> 6;
  const int r = lane & 31, half = lane >> 5;
  const int nt = blockIdx.x;              // 0..7: cal column tile
  f32x16 acc;
  #pragma unroll
  for (int i = 0; i < 16; ++i) acc[i] = 0.f;
  for (int ch = 0; ch < 2; ++ch) {        // two 512-K chunks of this block's 1024-K slice
    const size_t kbase = (size_t)blockIdx.y * 1024 + ch * 512;
    __syncthreads();
    #pragma unroll
    for (int s = 0; s < 16; ++s) {
      int flat = s * 256 + tid;           // 0..4095; <2048 = A, else B (wave-uniform per s)
      int rem = flat & 2047;
      int row = rem >> 6, kb = rem & 63;
      const unsigned short* src = (flat >= 2048)
          ? cbf + (size_t)(nt * 32 + row) * NPIX + kbase + kb * 8
          : tbf + (size_t)row * NPIX + kbase + kb * 8;
      int slot = ((kb << 5) + row) ^ (kb & 31);   // XOR swizzle breaks write-bank collisions
      int4 v = *(const int4*)src;
      *(int4*)((flat >= 2048 ? Bs : As) + slot * 8) = v;
    }
    __syncthreads();
    #pragma unroll
    for (int i = 0; i < 8; ++i) {         // wave's K-quarter: kblk in [wv*16, wv*16+16)
      int k8 = (wv << 4) + i * 2 + half;
      int slot = ((k8 << 5) + r) ^ (k8 & 31);
      bf16x8 a = *(const bf16x8*)(As + slot * 8);
      bf16x8 b = *(const bf16x8*)(Bs + slot * 8);
      acc = __builtin_amdgcn_mfma_f32_32x32x16_bf16(a, b, acc, 0, 0, 0);
    }
  }
  // C/D layout (HW-verified): col = lane&31, row = (reg&3) + 8*(reg>>2) + 4*(lane>>5)
  #pragma unroll
  for (int rg = 0; rg < 16; ++rg) {
    int m = (rg & 3) + 8 * (rg >> 2) + 4 * half;
    lred[wv][m * 32 + r] = acc[rg];
  }
  __syncthreads();
  float* gp = gpart + (size_t)(blockIdx.y * 8 + nt) * 1024;
  for (int e = tid; e < 1024; e += 256)
    gp[e] = lred[0][e] + lred[1][e] + lred[2][e] + lred[3][e];
}

// ---- weights + weighted-quantile + final scan + output, one block per test sample ----
// Absorbs k_tt (bit-exact: 1024 virtual threads on 512 real; virtual lanes == real
// lanes so both shfl trees and the 16-partial ordered sum are unchanged), k_finalp
// (integer counts, order-invariant) and k_out (writes out[] directly).
__global__ __launch_bounds__(512) void k_quantf(const float* __restrict__ gpart,
                                                const float* __restrict__ cc,
                                                const unsigned short* __restrict__ tbf,
                                                const unsigned* __restrict__ cdf,
                                                const unsigned short* __restrict__ grouped,
                                                const float* __restrict__ tres,
                                                const int* __restrict__ tgt,
                                                float* __restrict__ out) {
  __shared__ float qs[256];
  __shared__ float bins[4096];
  __shared__ float red[8];
  __shared__ float tpart[16];
  __shared__ float bc[6];      // [0]=wsum [1]=S(mid) [2]=tt [3]=thr [5]=lam
  __shared__ int ired[24];
  __shared__ unsigned sBin;
  const int b = blockIdx.x, tid = threadIdx.x;
  const int lane = tid & 63, wv = tid >> 6;

  for (int i = tid; i < 4096; i += 512) bins[i] = 0.f;
  if (tid == 0) sBin = 0xFFFFFFFFu;

  // ---- tt[b]: exact replica of the old 1024-thread reduction on 512 threads ----
  {
    const unsigned short* tbn = tbf + (size_t)b * NPIX;
    const int xa = tid & 255, ya = tid >> 8;        // virtual thread vt = tid
    const int yb = ya + 2;                          // virtual thread vt = tid + 512
    float sa = 0.f, sb = 0.f;
    #pragma unroll 4
    for (int it = 0; it < 64; ++it) {
      float ra = __uint_as_float((unsigned)tbn[((it * 4 + ya) << 8) + xa] << 16);
      float rb = __uint_as_float((unsigned)tbn[((it * 4 + yb) << 8) + xa] << 16);
      sa += ra * ra;
      sb += rb * rb;
    }
    #pragma unroll
    for (int off = 32; off; off >>= 1) {
      sa += __shfl_xor(sa, off);
      sb += __shfl_xor(sb, off);
    }
    if (lane == 0) { tpart[wv] = sa; tpart[8 + wv] = sb; }
  }
  __syncthreads();
  if (tid == 0) {
    float t = 0.f;
    for (int w = 0; w < 16; ++w) t += tpart[w];
    bc[2] = t;
  }
  // ---- weights g-sum (independent of tt) ----
  float g = 0.f;
  if (tid < 256) {
    const float* gp = gpart + ((tid >> 5) * 1024) + (b * 32) + (tid & 31);
    #pragma unroll 8
    for (int ks = 0; ks < 64; ++ks) g += gp[(size_t)ks * 8192];
  }
  __syncthreads();  // bc[2] visible
  float k = 0.f;
  if (tid < 256) {
    float d2 = bc[2] + cc[tid] - 2.f * g;
    k = expf(-d2 * (1.f / 8192.f));
  }
  float v = k;
  #pragma unroll
  for (int off = 32; off; off >>= 1) v += __shfl_xor(v, off);
  if (lane == 0) red[wv] = v;
  __syncthreads();
  if (tid == 0) {
    float ws = 1.f;
    for (int w = 0; w < 8; ++w) ws += red[w];
    bc[0] = ws;
  }
  __syncthreads();
  const float wsum = bc[0];
  const float wlast = 1.f / wsum;
  const float R = ALPHA - wlast;

  if (R > 0.f) {  // block-uniform branch: barriers inside are legal
    if (tid < 256) {
      unsigned pos = cdf[(size_t)tid * CDF_STRIDE + HB];
      qs[tid] = k / (wsum * (float)(pos ? pos : 1u));
    }
    __syncthreads();
    // ---- 14-step binary search over hi-16 buckets: invariant S(lo) < R <= S(hi) ----
    int lo = 0, hi = HB;
    float baseS = 0.f;
    for (int it = 0; it < 14; ++it) {
      int mid = (lo + hi) >> 1;
      float p = 0.f;
      if (tid < 256) p = qs[tid] * (float)cdf[(size_t)tid * CDF_STRIDE + mid];
      float r = p;
      #pragma unroll
      for (int off = 32; off; off >>= 1) r += __shfl_xor(r, off);
      if (lane == 0) red[wv] = r;
      __syncthreads();
      if (tid == 0) {
        float s = 0.f;
        for (int w = 0; w < 8; ++w) s += red[w];
        bc[1] = s;
      }
      __syncthreads();
      float S = bc[1];
      if (S < R) { lo = mid; baseS = S; } else { hi = mid; }
    }
    const int B = lo;  // crossing bucket; baseS = weighted count below it

    // ---- gather bucket B members into 4096-bin weighted histogram of lo16>>4 ----
    {
      const int n = tid >> 1;
      const float q = qs[n];
      const unsigned* cn = cdf + (size_t)n * CDF_STRIDE;
      const unsigned short* gn = grouped + (size_t)n * NPIX;
      unsigned e0 = cn[B + 1];
      for (unsigned j = cn[B] + (tid & 1); j < e0; j += 2)
        atomicAdd(&bins[gn[j] >> 4], q);
    }
    __syncthreads();

    // ---- wave 0: scan 4096 bins, find crossing bin ----
    if (wv == 0) {
      float s = 0.f;
      for (int j = 0; j < 64; ++j) s += bins[lane * 64 + j];
      float inc = s;
      #pragma unroll
      for (int off = 1; off < 64; off <<= 1) {
        float u = __shfl_up(inc, off);
        if (lane >= off) inc += u;
      }
      float pre = inc - s;
      bool hit = (baseS + pre < R) && (baseS + inc >= R);
      unsigned long long m = __ballot(hit);
      int ow = m ? (__ffsll((unsigned long long)m) - 1) : -1;
      if (lane == ow) {
        float run = baseS + pre;
        unsigned bin = (unsigned)lane * 64 + 63;
        for (int j = 0; j < 64; ++j) {
          float bv = bins[lane * 64 + j];
          if (run + bv >= R) { bin = (unsigned)lane * 64 + j; break; }
          run += bv;
        }
        sBin = bin;
      }
      if (m == 0 && lane == 0) sBin = 4095u;  // f32-rounding fallback
    }
    __syncthreads();
    if (tid == 0) {
      unsigned tb = ((unsigned)B << 16) | (sBin << 4);
      bc[5] = 1.0f - __uint_as_float(tb | 0x8u);   // lam: mid-bin representative
      bc[3] = __uint_as_float((tb | 0xFu) + 1u);   // thr: strictly above bin top
    }
  } else {
    // risk >= alpha for every lam -> lam=1, thr=0 (predict all)
    if (tid == 0) { bc[5] = 1.0f; bc[3] = 0.0f; }
  }
  __syncthreads();

  // ---- final scan (absorbed k_finalp): integer counts, order-invariant ----
  const float th = bc[3];
  const float4* rb4 = (const float4*)(tres + (size_t)b * NPIX);
  const int4* gb4 = (const int4*)(tgt + (size_t)b * NPIX);
  int sz = 0, tp = 0, tpos = 0;
  for (int i = tid; i < 16384; i += 512) {
    float4 r4 = rb4[i];
    int4 g4 = gb4[i];
    int p0 = (r4.x >= th), t0 = (g4.x > 0);
    int p1 = (r4.y >= th), t1 = (g4.y > 0);
    int p2 = (r4.z >= th), t2 = (g4.z > 0);
    int p3 = (r4.w >= th), t3 = (g4.w > 0);
    sz += p0 + p1 + p2 + p3;
    tp += (p0 & t0) + (p1 & t1) + (p2 & t2) + (p3 & t3);
    tpos += t0 + t1 + t2 + t3;
  }
  #pragma unroll
  for (int off = 32; off; off >>= 1) {
    sz += __shfl_xor(sz, off);
    tp += __shfl_xor(tp, off);
    tpos += __shfl_xor(tpos, off);
  }
  if (lane == 0) { ired[wv] = sz; ired[8 + wv] = tp; ired[16 + wv] = tpos; }
  __syncthreads();
  if (tid == 0) {
    int s0 = 0, s1 = 0, s2 = 0;
    for (int w = 0; w < 8; ++w) { s0 += ired[w]; s1 += ired[8 + w]; s2 += ired[16 + w]; }
    float tposf = (float)(s2 > 0 ? s2 : 1);
    out[b] = 1.f - (float)s1 / tposf;   // fnr_test
    out[32 + b] = bc[5];                // lambda
    out[64 + b] = (float)s0;            // size
  }
}

extern "C" void kernel_launch(void* const* d_in, const int* in_sizes, int n_in,
                              void* d_out, int out_size, void* d_ws, size_t ws_size,
                              hipStream_t stream) {
  const float* cal_feat = (const float*)d_in[0];
  const float* test_feat = (const float*)d_in[1];
  const int* cal_gt = (const int*)d_in[2];
  const int* test_gt = (const int*)d_in[3];
  float* out = (float*)d_out;
  char* ws = (char*)d_ws;

  float* test_res = (float*)(ws + OFF_TESTRES);
  unsigned short* cal_bf = (unsigned short*)(ws + OFF_CALBF);
  unsigned short* test_bf = (unsigned short*)(ws + OFF_TESTBF);
  unsigned short* grouped = (unsigned short*)(ws + OFF_GROUPED);
  unsigned* cdf = (unsigned*)(ws + OFF_CDF);
  float* gpart = (float*)(ws + OFF_GPART);
  float* cc = (float*)(ws + OFF_CC);

  k_calt<<<dim3(256), dim3(1024), 0, stream>>>(cal_feat, cal_gt, cal_bf, cdf, grouped, cc,
                                               test_feat, test_res, test_bf);
  k_gemm<<<dim3(8, 64), dim3(256), 0, stream>>>(test_bf, cal_bf, gpart);
  k_quantf<<<dim3(32), dim3(512), 0, stream>>>(gpart, cc, test_bf, cdf, grouped,
                                               test_res, test_gt, out);
}

// Round 5
// 242.650 us; speedup vs baseline: 1.0478x; 1.0478x over previous
//
#include <hip/hip_runtime.h>

// RandomlyLocalizedConformalRiskControl on MI355X.
// ws layout (bytes), total ~98.5 MB:
//   test_res f32 [32][65536]             @ 0          (8 MB)    f32 scores for final scan
//   cal_bf   u16 [256][65536]            @ 8388608    (32 MB)   bf16 cal scores (MFMA A/B)
//   test_bf  u16 [32][65536]             @ 41943040   (4 MB)    bf16 test scores
//   grouped  u16 [256][65536]            @ 46137344   (32 MB)   low-16 bits of f32 score, grouped by hi-16 bucket
//   cdf      u32 [256][CDF_STRIDE]       @ 79691776   (16 MB)   exclusive CDF over 16256 hi-16 buckets; [HB]=pos
//   gpart    f32 [64][8][1024]           @ 96354304   (2 MB)    split-K MFMA partials (deterministic)
//   cc f32[256], thr f32[32], lam f32[32], facc i32[32][4]
// Pipeline: k_calt -> k_gemm -> k_quantw (tt+weights+quantile) -> k_finalp (256-block
// parallel scan; R4 showed fusing it into the 32-block tail kernel serializes it) -> k_out.

#define NPIX 65536
#define HB 16256            // buckets = float_bits >> 16 for scores in (0, 1.0]
#define CDF_STRIDE 16272
#define ALPHA 0.1f
#define STAGE_CAP 35840     // u16 staging entries; pos ~ Bin(65536,1/2) max ~33.4K (+24 sigma)

#define OFF_TESTRES  0
#define OFF_CALBF    8388608u
#define OFF_TESTBF   41943040u
#define OFF_GROUPED  46137344u
#define OFF_CDF      79691776u
#define OFF_GPART    96354304u
#define OFF_CC       98451456u
#define OFF_THR      98452480u
#define OFF_LAM      98452608u
#define OFF_FACC     98452736u

typedef __attribute__((ext_vector_type(8))) short bf16x8;
typedef __attribute__((ext_vector_type(16))) float f32x16;

__device__ __forceinline__ unsigned short f2bf_rne(float f) {
  unsigned u = __float_as_uint(f);
  return (unsigned short)((u + 0x7FFFu + ((u >> 16) & 1u)) >> 16);
}

// XOR swizzle on bucket index: involution, closed within each 32-word block (HB is a
// multiple of 32), spreads stride-16 scan reads across banks. Unpacked 1-bucket/u32
// histogram: R3's 2-per-word packing halved the hot-word set (scores concentrate near
// 0.5) and raised same-address atomic serialization (conflicts 1.49M -> 2.24M) — reverted.
__device__ __forceinline__ int SW(int w) { return w ^ ((w >> 5) & 31); }

// Shared by phase A and phase B (and cal/test paths): identical inlined expression tree
// -> identical FMA contraction -> bit-identical f32 result on recompute.
// Independent per-call evaluation (no cross-iteration chain): R4's hprev chain serialized
// the unrolled loop (VALUBusy 51->44.6%, +4 us) — ILP beats FLOP-count here.
__device__ __forceinline__ float score_at(const float* __restrict__ sfeat,
                                          int x0, int x1, float wx, int y) {
  float sy = 0.25f * (float)y - 0.375f;
  int y0 = (int)floorf(sy);
  float wy = sy - (float)y0;
  int y1 = y0 + 1;
  if (y0 < 0) y0 = 0;
  if (y1 > 63) y1 = 63;
  float a = sfeat[y0 * 64 + x0] * (1.f - wx) + sfeat[y0 * 64 + x1] * wx;
  float b = sfeat[y1 * 64 + x0] * (1.f - wx) + sfeat[y1 * 64 + x1] * wx;
  float v = a * (1.f - wy) + b * wy;
  return 1.f / (1.f + __expf(-v));
}

// ---- fused cal+test features, 256 blocks (one per cal sample) ----
// Block n: cal sample n (hist + CDF + scatter + bf16 + cc) AND a 1/8 slice of test
// sample n>>3. tfeat ALIASES the staging buffer (test slice finishes before phase B's
// first staging write; separated by S1/S2/S2b/S3 barriers) so the unpacked 63.5 KB
// histogram + 70 KB staging + sfeat fit in 157.3 KB LDS.
// smem map (u32): [0,16256) hist -> CDF -> scatter counters (swizzled); [16256,16272)
// scan wave totals; [16272,16288) cc partials; [16288,17312) thread prefixes; [17312] pos.
__global__ __launch_bounds__(1024, 2) void k_calt(const float* __restrict__ featc,
                                                  const int* __restrict__ gt,
                                                  unsigned short* __restrict__ calbf,
                                                  unsigned* __restrict__ cdf,
                                                  unsigned short* __restrict__ grouped,
                                                  float* __restrict__ cc,
                                                  const float* __restrict__ featt,
                                                  float* __restrict__ tres,
                                                  unsigned short* __restrict__ tbf) {
  __shared__ unsigned smem[17313];
  __shared__ float sfeat[4096];
  __shared__ __align__(16) unsigned short sstage[STAGE_CAP];
  float* tfeat = (float*)sstage;  // first 16 KB; dead before phase B writes sstage
  const int tid = threadIdx.x;
  const int lane = tid & 63, wv = tid >> 6;
  const int x = tid & 255, yq = tid >> 8;  // yq in 0..3
  float sx = 0.25f * (float)x - 0.375f;
  int x0 = (int)floorf(sx);
  float wx = sx - (float)x0;
  int x1 = x0 + 1;
  if (x0 < 0) x0 = 0;
  if (x1 > 63) x1 = 63;

  const int n = blockIdx.x;
  const int b = n >> 3, sl = n & 7;  // test sample + slice handled by this block
  for (int i = tid; i < HB; i += 1024) smem[i] = 0;
  for (int i = tid; i < 4096; i += 1024) {
    sfeat[i] = featc[n * 4096 + i];
    tfeat[i] = featt[b * 4096 + i];
  }
  const int* gtn = gt + (size_t)n * NPIX;
  unsigned short* cbn = calbf + (size_t)n * NPIX;
  __syncthreads();  // S0: feats + hist zeroed

  // ---- test slice: pixels [sl*8192, (sl+1)*8192); x == tid&255 is preserved ----
  {
    float* resb = tres + (size_t)b * NPIX + sl * 8192;
    unsigned short* tbn = tbf + (size_t)b * NPIX + sl * 8192;
    #pragma unroll
    for (int i = 0; i < 8; ++i) {
      int y = sl * 32 + i * 4 + yq;
      float s = score_at(tfeat, x0, x1, wx, y);
      int q = i * 1024 + tid;
      resb[q] = s;
      tbn[q] = f2bf_rne(s);
    }
  }

  // ---- cal phase A: scores, bf16 write, hist atomics, cc ----
  unsigned long long pm = 0ull;
  float sumsq = 0.f;
  #pragma unroll 8
  for (int it = 0; it < 64; ++it) {
    int y = it * 4 + yq;
    float s = score_at(sfeat, x0, x1, wx, y);
    int p = (y << 8) + x;
    unsigned short bh = f2bf_rne(s);
    cbn[p] = bh;
    float sr = __uint_as_float((unsigned)bh << 16);
    sumsq += sr * sr;
    if (gtn[p] > 0) {
      pm |= (1ull << it);
      atomicAdd(&smem[SW((int)(__float_as_uint(s) >> 16))], 1u);
    }
  }
  // cc partials (16 waves), exact old summation order
  #pragma unroll
  for (int off = 32; off; off >>= 1) sumsq += __shfl_xor(sumsq, off);
  if (lane == 0) smem[16272 + wv] = __float_as_uint(sumsq);
  __syncthreads();  // S1: hist + cc partials final
  if (tid == 0) {
    float c = 0.f;
    for (int w = 0; w < 16; ++w) c += __uint_as_float(smem[16272 + w]);
    cc[n] = c;
  }
  // ---- exclusive scan: threads 0..1015, 16 buckets each ----
  const int base = tid * 16;
  unsigned psum = 0;
  if (tid < 1016) {
    #pragma unroll
    for (int j = 0; j < 16; ++j) psum += smem[SW(base + j)];
  }
  unsigned inc = psum;
  #pragma unroll
  for (int off = 1; off < 64; off <<= 1) {
    unsigned v = __shfl_up(inc, off);
    if (lane >= off) inc += v;
  }
  if (lane == 63) smem[16256 + wv] = inc;  // wave totals
  smem[16288 + tid] = inc - psum;          // thread-exclusive prefix within wave
  __syncthreads();  // S2: totals + prefixes ready
  {
    unsigned woff = 0;
    for (int w = 0; w < wv; ++w) woff += smem[16256 + w];  // broadcast reads
    unsigned run = woff + smem[16288 + tid];
    if (tid < 1016) {
      #pragma unroll
      for (int j = 0; j < 16; ++j) {
        int si = SW(base + j);
        unsigned h = smem[si];
        smem[si] = run;  // exclusive CDF -> scatter counters
        run += h;
      }
    }
    if (tid == 1015) smem[17312] = run;  // total positives (lanes above 1015 hold 0)
  }
  __syncthreads();  // S2b: counters final
  // ---- COALESCED cdf copyout ----
  unsigned* cdfn = cdf + (size_t)n * CDF_STRIDE;
  for (int i = tid; i < HB; i += 1024) cdfn[i] = smem[SW(i)];
  const unsigned pos = smem[17312];
  if (tid == 0) cdfn[HB] = pos;
  __syncthreads();  // S3: cdf written before counters mutate
  // ---- phase B: recompute scores (bit-exact via shared score_at), LDS staging ----
  unsigned short* gn = grouped + (size_t)n * NPIX;
  for (int it = 0; it < 64; ++it) {
    if (pm & (1ull << it)) {
      int y = it * 4 + yq;
      float s = score_at(sfeat, x0, x1, wx, y);
      unsigned bits = __float_as_uint(s);
      unsigned idx = atomicAdd(&smem[SW((int)(bits >> 16))], 1u);
      unsigned short lo = (unsigned short)(bits & 0xFFFFu);
      if (idx < STAGE_CAP) sstage[idx] = lo;
      else gn[idx] = lo;  // overflow fallback: same final location, direct store
    }
  }
  __syncthreads();  // S4: staging complete
  // ---- COALESCED grouped copyout ----
  unsigned lim = pos < STAGE_CAP ? pos : STAGE_CAP;
  for (unsigned i = tid; i < lim; i += 1024) gn[i] = sstage[i];
}

// ---- LDS-staged bf16 MFMA GEMM: gpart[ks][nt][m*32+nl] = <test_m, cal_(nt*32+nl)> ----
// Coalesced 1KB/wave global loads into XOR-swizzled [kblk][row][16B] tiles; ds_read_b128
// fragments; wave = K-quarter split, cross-wave reduce in lred. 80 KB LDS -> 2 blocks/CU.
__global__ __launch_bounds__(256) void k_gemm(const unsigned short* __restrict__ tbf,
                                              const unsigned short* __restrict__ cbf,
                                              float* __restrict__ gpart) {
  __shared__ __align__(16) unsigned short As[16384];  // 32 KB: 64 kblk x 32 row x 8 elems
  __shared__ __align__(16) unsigned short Bs[16384];
  __shared__ float lred[4][1024];                     // 16 KB
  const int tid = threadIdx.x;
  const int lane = tid & 63, wv = tid >> 6;
  const int r = lane & 31, half = lane >> 5;
  const int nt = blockIdx.x;              // 0..7: cal column tile
  f32x16 acc;
  #pragma unroll
  for (int i = 0; i < 16; ++i) acc[i] = 0.f;
  for (int ch = 0; ch < 2; ++ch) {        // two 512-K chunks of this block's 1024-K slice
    const size_t kbase = (size_t)blockIdx.y * 1024 + ch * 512;
    __syncthreads();
    #pragma unroll
    for (int s = 0; s < 16; ++s) {
      int flat = s * 256 + tid;           // 0..4095; <2048 = A, else B (wave-uniform per s)
      int rem = flat & 2047;
      int row = rem >> 6, kb = rem & 63;
      const unsigned short* src = (flat >= 2048)
          ? cbf + (size_t)(nt * 32 + row) * NPIX + kbase + kb * 8
          : tbf + (size_t)row * NPIX + kbase + kb * 8;
      int slot = ((kb << 5) + row) ^ (kb & 31);   // XOR swizzle breaks write-bank collisions
      int4 v = *(const int4*)src;
      *(int4*)((flat >= 2048 ? Bs : As) + slot * 8) = v;
    }
    __syncthreads();
    #pragma unroll
    for (int i = 0; i < 8; ++i) {         // wave's K-quarter: kblk in [wv*16, wv*16+16)
      int k8 = (wv << 4) + i * 2 + half;
      int slot = ((k8 << 5) + r) ^ (k8 & 31);
      bf16x8 a = *(const bf16x8*)(As + slot * 8);
      bf16x8 b = *(const bf16x8*)(Bs + slot * 8);
      acc = __builtin_amdgcn_mfma_f32_32x32x16_bf16(a, b, acc, 0, 0, 0);
    }
  }
  // C/D layout (HW-verified): col = lane&31, row = (reg&3) + 8*(reg>>2) + 4*(lane>>5)
  #pragma unroll
  for (int rg = 0; rg < 16; ++rg) {
    int m = (rg & 3) + 8 * (rg >> 2) + 4 * half;
    lred[wv][m * 32 + r] = acc[rg];
  }
  __syncthreads();
  float* gp = gpart + (size_t)(blockIdx.y * 8 + nt) * 1024;
  for (int e = tid; e < 1024; e += 256)
    gp[e] = lred[0][e] + lred[1][e] + lred[2][e] + lred[3][e];
}

// ---- tt + weights + weighted-quantile; zero-inits facc; writes thr/lam ----
// tt is the bit-exact virtual-thread replica of the original 1024-thread reduction
// (virtual lanes == real lanes: shfl trees and 16-partial ordered sum unchanged).
__global__ __launch_bounds__(512) void k_quantw(const float* __restrict__ gpart,
                                                const float* __restrict__ cc,
                                                const unsigned short* __restrict__ tbf,
                                                const unsigned* __restrict__ cdf,
                                                const unsigned short* __restrict__ grouped,
                                                float* __restrict__ lam,
                                                float* __restrict__ thr,
                                                int* __restrict__ facc) {
  __shared__ float qs[256];
  __shared__ float bins[4096];
  __shared__ float red[8];
  __shared__ float tpart[16];
  __shared__ float bc[3];      // [0]=wsum [1]=S(mid) [2]=tt
  __shared__ unsigned sBin;
  const int b = blockIdx.x, tid = threadIdx.x;
  const int lane = tid & 63, wv = tid >> 6;

  if (tid < 4) facc[b * 4 + tid] = 0;
  for (int i = tid; i < 4096; i += 512) bins[i] = 0.f;
  if (tid == 0) sBin = 0xFFFFFFFFu;

  // ---- tt[b]: exact replica of the old 1024-thread reduction on 512 threads ----
  {
    const unsigned short* tbn = tbf + (size_t)b * NPIX;
    const int xa = tid & 255, ya = tid >> 8;        // virtual thread vt = tid
    const int yb = ya + 2;                          // virtual thread vt = tid + 512
    float sa = 0.f, sb = 0.f;
    #pragma unroll 4
    for (int it = 0; it < 64; ++it) {
      float ra = __uint_as_float((unsigned)tbn[((it * 4 + ya) << 8) + xa] << 16);
      float rb = __uint_as_float((unsigned)tbn[((it * 4 + yb) << 8) + xa] << 16);
      sa += ra * ra;
      sb += rb * rb;
    }
    #pragma unroll
    for (int off = 32; off; off >>= 1) {
      sa += __shfl_xor(sa, off);
      sb += __shfl_xor(sb, off);
    }
    if (lane == 0) { tpart[wv] = sa; tpart[8 + wv] = sb; }
  }
  __syncthreads();
  if (tid == 0) {
    float t = 0.f;
    for (int w = 0; w < 16; ++w) t += tpart[w];
    bc[2] = t;
  }
  // ---- weights g-sum (independent of tt) ----
  float g = 0.f;
  if (tid < 256) {
    const float* gp = gpart + ((tid >> 5) * 1024) + (b * 32) + (tid & 31);
    #pragma unroll 8
    for (int ks = 0; ks < 64; ++ks) g += gp[(size_t)ks * 8192];
  }
  __syncthreads();  // bc[2] visible
  float k = 0.f;
  if (tid < 256) {
    float d2 = bc[2] + cc[tid] - 2.f * g;
    k = expf(-d2 * (1.f / 8192.f));
  }
  float v = k;
  #pragma unroll
  for (int off = 32; off; off >>= 1) v += __shfl_xor(v, off);
  if (lane == 0) red[wv] = v;
  __syncthreads();
  if (tid == 0) {
    float ws = 1.f;
    for (int w = 0; w < 8; ++w) ws += red[w];
    bc[0] = ws;
  }
  __syncthreads();
  const float wsum = bc[0];
  const float wlast = 1.f / wsum;
  const float R = ALPHA - wlast;
  if (R <= 0.f) {  // risk >= alpha for every lam -> low -> 1.0f, thr 0 (predict all)
    if (tid == 0) { lam[b] = 1.0f; thr[b] = 0.0f; }
    return;
  }
  if (tid < 256) {
    unsigned pos = cdf[(size_t)tid * CDF_STRIDE + HB];
    qs[tid] = k / (wsum * (float)(pos ? pos : 1u));
  }
  __syncthreads();

  // ---- 14-step binary search over hi-16 buckets: invariant S(lo) < R <= S(hi) ----
  int lo = 0, hi = HB;
  float baseS = 0.f;
  for (int it = 0; it < 14; ++it) {
    int mid = (lo + hi) >> 1;
    float p = 0.f;
    if (tid < 256) p = qs[tid] * (float)cdf[(size_t)tid * CDF_STRIDE + mid];
    float r = p;
    #pragma unroll
    for (int off = 32; off; off >>= 1) r += __shfl_xor(r, off);
    if (lane == 0) red[wv] = r;
    __syncthreads();
    if (tid == 0) {
      float s = 0.f;
      for (int w = 0; w < 8; ++w) s += red[w];
      bc[1] = s;
    }
    __syncthreads();
    float S = bc[1];
    if (S < R) { lo = mid; baseS = S; } else { hi = mid; }
  }
  const int B = lo;  // crossing bucket; baseS = weighted count below it

  // ---- gather bucket B members into 4096-bin weighted histogram of lo16>>4 ----
  {
    const int n = tid >> 1;
    const float q = qs[n];
    const unsigned* cn = cdf + (size_t)n * CDF_STRIDE;
    const unsigned short* gn = grouped + (size_t)n * NPIX;
    unsigned e0 = cn[B + 1];
    for (unsigned j = cn[B] + (tid & 1); j < e0; j += 2)
      atomicAdd(&bins[gn[j] >> 4], q);
  }
  __syncthreads();

  // ---- wave 0: scan 4096 bins, find crossing bin ----
  if (wv == 0) {
    float s = 0.f;
    for (int j = 0; j < 64; ++j) s += bins[lane * 64 + j];
    float inc = s;
    #pragma unroll
    for (int off = 1; off < 64; off <<= 1) {
      float u = __shfl_up(inc, off);
      if (lane >= off) inc += u;
    }
    float pre = inc - s;
    bool hit = (baseS + pre < R) && (baseS + inc >= R);
    unsigned long long m = __ballot(hit);
    int ow = m ? (__ffsll((unsigned long long)m) - 1) : -1;
    if (lane == ow) {
      float run = baseS + pre;
      unsigned bin = (unsigned)lane * 64 + 63;
      for (int j = 0; j < 64; ++j) {
        float bv = bins[lane * 64 + j];
        if (run + bv >= R) { bin = (unsigned)lane * 64 + j; break; }
        run += bv;
      }
      sBin = bin;
    }
    if (m == 0 && lane == 0) sBin = 4095u;  // f32-rounding fallback (unreachable in practice)
  }
  __syncthreads();
  if (tid == 0) {
    unsigned tb = ((unsigned)B << 16) | (sBin << 4);
    lam[b] = 1.0f - __uint_as_float(tb | 0x8u);     // mid-bin representative
    thr[b] = __uint_as_float((tb | 0xFu) + 1u);     // strictly above bin top: pred = res > u*
  }
}

// ---- final partials: grid (32 samples, 8 segments), atomic int accumulate ----
// float4/int4 loads: integer reductions are mapping-invariant -> bit-exact outputs.
__global__ __launch_bounds__(256) void k_finalp(const float* __restrict__ tres,
                                                const int* __restrict__ tgt,
                                                const float* __restrict__ thr,
                                                int* __restrict__ facc) {
  __shared__ int red[12];
  const int b = blockIdx.x, seg = blockIdx.y, tid = threadIdx.x;
  const int lane = tid & 63, wv = tid >> 6;
  const float th = thr[b];
  const float4* rb4 = (const float4*)(tres + (size_t)b * NPIX + seg * 8192);
  const int4* gb4 = (const int4*)(tgt + (size_t)b * NPIX + seg * 8192);
  int sz = 0, tp = 0, tpos = 0;
  #pragma unroll
  for (int i = 0; i < 8; ++i) {
    float4 r4 = rb4[i * 256 + tid];
    int4 g4 = gb4[i * 256 + tid];
    int p0 = (r4.x >= th), t0 = (g4.x > 0);
    int p1 = (r4.y >= th), t1 = (g4.y > 0);
    int p2 = (r4.z >= th), t2 = (g4.z > 0);
    int p3 = (r4.w >= th), t3 = (g4.w > 0);
    sz += p0 + p1 + p2 + p3;
    tp += (p0 & t0) + (p1 & t1) + (p2 & t2) + (p3 & t3);
    tpos += t0 + t1 + t2 + t3;
  }
  #pragma unroll
  for (int off = 32; off; off >>= 1) {
    sz += __shfl_xor(sz, off);
    tp += __shfl_xor(tp, off);
    tpos += __shfl_xor(tpos, off);
  }
  if (lane == 0) { red[wv] = sz; red[4 + wv] = tp; red[8 + wv] = tpos; }
  __syncthreads();
  if (tid == 0) {
    int s0 = red[0] + red[1] + red[2] + red[3];
    int s1 = red[4] + red[5] + red[6] + red[7];
    int s2 = red[8] + red[9] + red[10] + red[11];
    atomicAdd(&facc[b * 4 + 0], s0);
    atomicAdd(&facc[b * 4 + 1], s1);
    atomicAdd(&facc[b * 4 + 2], s2);
  }
}

// ---- emit outputs ----
__global__ void k_out(const int* __restrict__ facc, const float* __restrict__ lam,
                      float* __restrict__ out) {
  int b = threadIdx.x;
  if (b < 32) {
    int sz = facc[b * 4], tp = facc[b * 4 + 1], tpos = facc[b * 4 + 2];
    float tposf = (float)(tpos > 0 ? tpos : 1);
    out[b] = 1.f - (float)tp / tposf;   // fnr_test
    out[32 + b] = lam[b];               // lambda
    out[64 + b] = (float)sz;            // size
  }
}

extern "C" void kernel_launch(void* const* d_in, const int* in_sizes, int n_in,
                              void* d_out, int out_size, void* d_ws, size_t ws_size,
                              hipStream_t stream) {
  const float* cal_feat = (const float*)d_in[0];
  const float* test_feat = (const float*)d_in[1];
  const int* cal_gt = (const int*)d_in[2];
  const int* test_gt = (const int*)d_in[3];
  float* out = (float*)d_out;
  char* ws = (char*)d_ws;

  float* test_res = (float*)(ws + OFF_TESTRES);
  unsigned short* cal_bf = (unsigned short*)(ws + OFF_CALBF);
  unsigned short* test_bf = (unsigned short*)(ws + OFF_TESTBF);
  unsigned short* grouped = (unsigned short*)(ws + OFF_GROUPED);
  unsigned* cdf = (unsigned*)(ws + OFF_CDF);
  float* gpart = (float*)(ws + OFF_GPART);
  float* cc = (float*)(ws + OFF_CC);
  float* thr = (float*)(ws + OFF_THR);
  float* lam = (float*)(ws + OFF_LAM);
  int* facc = (int*)(ws + OFF_FACC);

  k_calt<<<dim3(256), dim3(1024), 0, stream>>>(cal_feat, cal_gt, cal_bf, cdf, grouped, cc,
                                               test_feat, test_res, test_bf);
  k_gemm<<<dim3(8, 64), dim3(256), 0, stream>>>(test_bf, cal_bf, gpart);
  k_quantw<<<dim3(32), dim3(512), 0, stream>>>(gpart, cc, test_bf, cdf, grouped,
                                               lam, thr, facc);
  k_finalp<<<dim3(32, 8), dim3(256), 0, stream>>>(test_res, test_gt, thr, facc);
  k_out<<<dim3(1), dim3(64), 0, stream>>>(facc, lam, out);
}

// Round 6
// 239.671 us; speedup vs baseline: 1.0608x; 1.0124x over previous
//
#include <hip/hip_runtime.h>

// RandomlyLocalizedConformalRiskControl on MI355X.
// ws layout (bytes), total ~90.1 MB:
//   test_res f32 [32][65536]             @ 0          (8 MB)    f32 scores for final scan
//   cal_bf   u16 [256][65536]            @ 8388608    (32 MB)   bf16 cal scores (MFMA A/B)
//   test_bf  u16 [32][65536]             @ 41943040   (4 MB)    bf16 test scores
//   grouped  u16 [256][65536]            @ 46137344   (32 MB)   low-16 bits of f32 score, grouped by hi-16 bucket
//   cdf      u16 [256][CDF_STRIDE]       @ 79691776   (8.3 MB)  exclusive CDF over 16256 hi-16 buckets; [HB]=pos
//                                                               (counts <= ~34K < 2^16; u16->f32 exact)
//   gpart    f32 [64][8][1024]           @ 88023040   (2 MB)    split-K MFMA partials (deterministic)
//   cc f32[256], thr f32[32], lam f32[32], facc i32[32][4]
// Pipeline: k_calt -> k_gemm -> k_quantw -> k_finalp (absorbs k_out via completion counter).

#define NPIX 65536
#define HB 16256            // buckets = float_bits >> 16 for scores in (0, 1.0]
#define CDF_STRIDE 16272
#define ALPHA 0.1f
#define STAGE_CAP 35840     // u16 staging entries; pos ~ Bin(65536,1/2) max ~33.4K (+24 sigma)

#define OFF_TESTRES  0
#define OFF_CALBF    8388608u
#define OFF_TESTBF   41943040u
#define OFF_GROUPED  46137344u
#define OFF_CDF      79691776u
#define OFF_GPART    88023040u
#define OFF_CC       90120192u
#define OFF_THR      90121216u
#define OFF_LAM      90121344u
#define OFF_FACC     90121472u

typedef __attribute__((ext_vector_type(8))) short bf16x8;
typedef __attribute__((ext_vector_type(16))) float f32x16;

__device__ __forceinline__ unsigned short f2bf_rne(float f) {
  unsigned u = __float_as_uint(f);
  return (unsigned short)((u + 0x7FFFu + ((u >> 16) & 1u)) >> 16);
}

// XOR swizzle on bucket index: involution, closed within each 32-word block.
__device__ __forceinline__ int SW(int w) { return w ^ ((w >> 5) & 31); }

// The sigmoid tail shared by ALL score evaluation sites: identical inlined expression
// tree -> identical FMA contraction -> bit-identical f32 on every recompute/reuse.
__device__ __forceinline__ float sig_v(float a, float b, float wy) {
  float v = a * (1.f - wy) + b * wy;
  return 1.f / (1.f + __expf(-v));
}

// ---- fused cal+test features, 256 blocks (one per cal sample) ----
// BANDED remap (R6): thread (x,yq) owns a CONTIGUOUS 64-row band [64yq, 64yq+64).
// Rows 4m..4m+3 ("quad" m) bilinear-interp from feature rows m-1, m, m+1 only, so a
// rolling 3-register window gives 18 row-interp evals per 64 scores (vs 128) with 4
// independent sigmoids per quad — R4's chain killed ILP (serial dep); quads keep it.
// wy = sy - floor(sy) is exact dyadic => identical bits to the old per-call values;
// row-interp values are reused (deterministic identical), so every stored score is
// bit-identical to R5. Only cc's accumulation order changes (ulp-level; the pipeline
// already tolerates nondeterministic f32 atomics in k_quantw's bins at absmax=0).
// smem map (u32): [0,16256) hist -> CDF -> scatter counters (swizzled); [16256,16272)
// scan wave totals; [16272,16288) cc partials; [16288,17312) thread prefixes; [17312] pos.
__global__ __launch_bounds__(1024, 2) void k_calt(const float* __restrict__ featc,
                                                  const int* __restrict__ gt,
                                                  unsigned short* __restrict__ calbf,
                                                  unsigned short* __restrict__ cdf,
                                                  unsigned short* __restrict__ grouped,
                                                  float* __restrict__ cc,
                                                  const float* __restrict__ featt,
                                                  float* __restrict__ tres,
                                                  unsigned short* __restrict__ tbf) {
  __shared__ unsigned smem[17313];
  __shared__ float sfeat[4096];
  __shared__ __align__(16) unsigned short sstage[STAGE_CAP];
  float* tfeat = (float*)sstage;  // first 16 KB; dead before phase B writes sstage
  const int tid = threadIdx.x;
  const int lane = tid & 63, wv = tid >> 6;
  const int x = tid & 255, yq = tid >> 8;  // yq in 0..3
  float sx = 0.25f * (float)x - 0.375f;
  int x0 = (int)floorf(sx);
  float wx = sx - (float)x0;
  int x1 = x0 + 1;
  if (x0 < 0) x0 = 0;
  if (x1 > 63) x1 = 63;

  const int n = blockIdx.x;
  const int b = n >> 3, sl = n & 7;  // test sample + slice handled by this block
  for (int i = tid; i < HB; i += 1024) smem[i] = 0;
  for (int i = tid; i < 4096; i += 1024) {
    sfeat[i] = featc[n * 4096 + i];
    tfeat[i] = featt[b * 4096 + i];
  }
  const int* gtn = gt + (size_t)n * NPIX;
  unsigned short* cbn = calbf + (size_t)n * NPIX;
  __syncthreads();  // S0: feats + hist zeroed

  // ---- test slice: rows [sl*32+8yq, +8) = quads mt0, mt0+1 ----
  {
    const float* tf0 = tfeat + x0;
    const float* tf1 = tfeat + x1;
    float* resb = tres + (size_t)b * NPIX;
    unsigned short* tbn = tbf + (size_t)b * NPIX;
    const int mt0 = sl * 8 + yq * 2;
    int rp = mt0 - 1 < 0 ? 0 : mt0 - 1;
    float hp = tf0[rp * 64] * (1.f - wx) + tf1[rp * 64] * wx;
    float hc = tf0[mt0 * 64] * (1.f - wx) + tf1[mt0 * 64] * wx;
    #pragma unroll
    for (int q = 0; q < 2; ++q) {
      int m = mt0 + q;
      int rn = m + 1 > 63 ? 63 : m + 1;
      float hn = tf0[rn * 64] * (1.f - wx) + tf1[rn * 64] * wx;
      #pragma unroll
      for (int j = 0; j < 4; ++j) {
        int y = 4 * m + j;
        float sy = 0.25f * (float)y - 0.375f;
        int y0 = (int)floorf(sy);
        float wy = sy - (float)y0;            // exact dyadic: {.625,.875,.125,.375}
        float s = sig_v(j < 2 ? hp : hc, j < 2 ? hc : hn, wy);
        int p = (y << 8) + x;
        resb[p] = s;
        tbn[p] = f2bf_rne(s);
      }
      hp = hc; hc = hn;
    }
  }

  // ---- cal phase A: banded scores, bf16 write, hist atomics, cc ----
  const float* f0 = sfeat + x0;
  const float* f1 = sfeat + x1;
  const int m0 = yq * 16;  // first quad of this thread's band
  unsigned long long pm = 0ull;
  float sumsq = 0.f;
  {
    int rp = m0 - 1 < 0 ? 0 : m0 - 1;
    float hp = f0[rp * 64] * (1.f - wx) + f1[rp * 64] * wx;
    float hc = f0[m0 * 64] * (1.f - wx) + f1[m0 * 64] * wx;
    #pragma unroll 4
    for (int q = 0; q < 16; ++q) {
      int m = m0 + q;
      int rn = m + 1 > 63 ? 63 : m + 1;
      float hn = f0[rn * 64] * (1.f - wx) + f1[rn * 64] * wx;
      #pragma unroll
      for (int j = 0; j < 4; ++j) {
        int y = 4 * m + j;
        float sy = 0.25f * (float)y - 0.375f;
        int y0 = (int)floorf(sy);
        float wy = sy - (float)y0;
        float s = sig_v(j < 2 ? hp : hc, j < 2 ? hc : hn, wy);
        int p = (y << 8) + x;
        unsigned short bh = f2bf_rne(s);
        cbn[p] = bh;
        float sr = __uint_as_float((unsigned)bh << 16);
        sumsq += sr * sr;
        if (gtn[p] > 0) {
          pm |= (1ull << (q * 4 + j));
          atomicAdd(&smem[SW((int)(__float_as_uint(s) >> 16))], 1u);
        }
      }
      hp = hc; hc = hn;
    }
  }
  // cc partials (16 waves); accumulation order = band order (reassociated vs R5,
  // accepted: same ulp class as the already-nondeterministic bins atomics)
  #pragma unroll
  for (int off = 32; off; off >>= 1) sumsq += __shfl_xor(sumsq, off);
  if (lane == 0) smem[16272 + wv] = __float_as_uint(sumsq);
  __syncthreads();  // S1: hist + cc partials final
  if (tid == 0) {
    float c = 0.f;
    for (int w = 0; w < 16; ++w) c += __uint_as_float(smem[16272 + w]);
    cc[n] = c;
  }
  // ---- exclusive scan: threads 0..1015, 16 buckets each ----
  const int base = tid * 16;
  unsigned psum = 0;
  if (tid < 1016) {
    #pragma unroll
    for (int j = 0; j < 16; ++j) psum += smem[SW(base + j)];
  }
  unsigned inc = psum;
  #pragma unroll
  for (int off = 1; off < 64; off <<= 1) {
    unsigned v = __shfl_up(inc, off);
    if (lane >= off) inc += v;
  }
  if (lane == 63) smem[16256 + wv] = inc;  // wave totals
  smem[16288 + tid] = inc - psum;          // thread-exclusive prefix within wave
  __syncthreads();  // S2: totals + prefixes ready
  {
    unsigned woff = 0;
    for (int w = 0; w < wv; ++w) woff += smem[16256 + w];  // broadcast reads
    unsigned run = woff + smem[16288 + tid];
    if (tid < 1016) {
      #pragma unroll
      for (int j = 0; j < 16; ++j) {
        int si = SW(base + j);
        unsigned h = smem[si];
        smem[si] = run;  // exclusive CDF -> scatter counters
        run += h;
      }
    }
    if (tid == 1015) smem[17312] = run;  // total positives (lanes above 1015 hold 0)
  }
  __syncthreads();  // S2b: counters final
  // ---- COALESCED u16 cdf copyout ----
  unsigned short* cdfn = cdf + (size_t)n * CDF_STRIDE;
  for (int i = tid; i < HB; i += 1024) cdfn[i] = (unsigned short)smem[SW(i)];
  const unsigned pos = smem[17312];
  if (tid == 0) cdfn[HB] = (unsigned short)pos;  // pos < 2^16 for Bin(65536,1/2) data
  __syncthreads();  // S3: cdf written before counters mutate
  // ---- phase B: banded recompute (bit-exact reuse structure), LDS staging ----
  unsigned short* gn = grouped + (size_t)n * NPIX;
  {
    int rp = m0 - 1 < 0 ? 0 : m0 - 1;
    float hp = f0[rp * 64] * (1.f - wx) + f1[rp * 64] * wx;
    float hc = f0[m0 * 64] * (1.f - wx) + f1[m0 * 64] * wx;
    for (int q = 0; q < 16; ++q) {
      int m = m0 + q;
      int rn = m + 1 > 63 ? 63 : m + 1;
      float hn = f0[rn * 64] * (1.f - wx) + f1[rn * 64] * wx;
      unsigned nib = (unsigned)(pm >> (q * 4)) & 0xFu;
      if (nib) {
        #pragma unroll
        for (int j = 0; j < 4; ++j) {
          if (nib & (1u << j)) {
            int y = 4 * m + j;
            float sy = 0.25f * (float)y - 0.375f;
            int y0 = (int)floorf(sy);
            float wy = sy - (float)y0;
            float s = sig_v(j < 2 ? hp : hc, j < 2 ? hc : hn, wy);
            unsigned bits = __float_as_uint(s);
            unsigned idx = atomicAdd(&smem[SW((int)(bits >> 16))], 1u);
            unsigned short lo = (unsigned short)(bits & 0xFFFFu);
            if (idx < STAGE_CAP) sstage[idx] = lo;
            else gn[idx] = lo;  // overflow fallback: same final location
          }
        }
      }
      hp = hc; hc = hn;
    }
  }
  __syncthreads();  // S4: staging complete
  // ---- COALESCED grouped copyout ----
  unsigned lim = pos < STAGE_CAP ? pos : STAGE_CAP;
  for (unsigned i = tid; i < lim; i += 1024) gn[i] = sstage[i];
}

// ---- LDS-staged bf16 MFMA GEMM: gpart[ks][nt][m*32+nl] = <test_m, cal_(nt*32+nl)> ----
__global__ __launch_bounds__(256) void k_gemm(const unsigned short* __restrict__ tbf,
                                              const unsigned short* __restrict__ cbf,
                                              float* __restrict__ gpart) {
  __shared__ __align__(16) unsigned short As[16384];  // 32 KB: 64 kblk x 32 row x 8 elems
  __shared__ __align__(16) unsigned short Bs[16384];
  __shared__ float lred[4][1024];                     // 16 KB
  const int tid = threadIdx.x;
  const int lane = tid & 63, wv = tid >> 6;
  const int r = lane & 31, half = lane >> 5;
  const int nt = blockIdx.x;              // 0..7: cal column tile
  f32x16 acc;
  #pragma unroll
  for (int i = 0; i < 16; ++i) acc[i] = 0.f;
  for (int ch = 0; ch < 2; ++ch) {        // two 512-K chunks of this block's 1024-K slice
    const size_t kbase = (size_t)blockIdx.y * 1024 + ch * 512;
    __syncthreads();
    #pragma unroll
    for (int s = 0; s < 16; ++s) {
      int flat = s * 256 + tid;           // 0..4095; <2048 = A, else B (wave-uniform per s)
      int rem = flat & 2047;
      int row = rem >> 6, kb = rem & 63;
      const unsigned short* src = (flat >= 2048)
          ? cbf + (size_t)(nt * 32 + row) * NPIX + kbase + kb * 8
          : tbf + (size_t)row * NPIX + kbase + kb * 8;
      int slot = ((kb << 5) + row) ^ (kb & 31);   // XOR swizzle breaks write-bank collisions
      int4 v = *(const int4*)src;
      *(int4*)((flat >= 2048 ? Bs : As) + slot * 8) = v;
    }
    __syncthreads();
    #pragma unroll
    for (int i = 0; i < 8; ++i) {         // wave's K-quarter: kblk in [wv*16, wv*16+16)
      int k8 = (wv << 4) + i * 2 + half;
      int slot = ((k8 << 5) + r) ^ (k8 & 31);
      bf16x8 a = *(const bf16x8*)(As + slot * 8);
      bf16x8 b = *(const bf16x8*)(Bs + slot * 8);
      acc = __builtin_amdgcn_mfma_f32_32x32x16_bf16(a, b, acc, 0, 0, 0);
    }
  }
  // C/D layout (HW-verified): col = lane&31, row = (reg&3) + 8*(reg>>2) + 4*(lane>>5)
  #pragma unroll
  for (int rg = 0; rg < 16; ++rg) {
    int m = (rg & 3) + 8 * (rg >> 2) + 4 * half;
    lred[wv][m * 32 + r] = acc[rg];
  }
  __syncthreads();
  float* gp = gpart + (size_t)(blockIdx.y * 8 + nt) * 1024;
  for (int e = tid; e < 1024; e += 256)
    gp[e] = lred[0][e] + lred[1][e] + lred[2][e] + lred[3][e];
}

// ---- tt + weights + weighted-quantile; zero-inits facc; writes thr/lam ----
__global__ __launch_bounds__(512) void k_quantw(const float* __restrict__ gpart,
                                                const float* __restrict__ cc,
                                                const unsigned short* __restrict__ tbf,
                                                const unsigned short* __restrict__ cdf,
                                                const unsigned short* __restrict__ grouped,
                                                float* __restrict__ lam,
                                                float* __restrict__ thr,
                                                int* __restrict__ facc) {
  __shared__ float qs[256];
  __shared__ float bins[4096];
  __shared__ float red[8];
  __shared__ float tpart[16];
  __shared__ float bc[3];      // [0]=wsum [1]=S(mid) [2]=tt
  __shared__ unsigned sBin;
  const int b = blockIdx.x, tid = threadIdx.x;
  const int lane = tid & 63, wv = tid >> 6;

  if (tid < 4) facc[b * 4 + tid] = 0;
  for (int i = tid; i < 4096; i += 512) bins[i] = 0.f;
  if (tid == 0) sBin = 0xFFFFFFFFu;

  // ---- tt[b]: bit-exact virtual-thread replica of the original 1024-thread reduction ----
  {
    const unsigned short* tbn = tbf + (size_t)b * NPIX;
    const int xa = tid & 255, ya = tid >> 8;        // virtual thread vt = tid
    const int yb = ya + 2;                          // virtual thread vt = tid + 512
    float sa = 0.f, sb = 0.f;
    #pragma unroll 4
    for (int it = 0; it < 64; ++it) {
      float ra = __uint_as_float((unsigned)tbn[((it * 4 + ya) << 8) + xa] << 16);
      float rb = __uint_as_float((unsigned)tbn[((it * 4 + yb) << 8) + xa] << 16);
      sa += ra * ra;
      sb += rb * rb;
    }
    #pragma unroll
    for (int off = 32; off; off >>= 1) {
      sa += __shfl_xor(sa, off);
      sb += __shfl_xor(sb, off);
    }
    if (lane == 0) { tpart[wv] = sa; tpart[8 + wv] = sb; }
  }
  __syncthreads();
  if (tid == 0) {
    float t = 0.f;
    for (int w = 0; w < 16; ++w) t += tpart[w];
    bc[2] = t;
  }
  // ---- weights g-sum (independent of tt) ----
  float g = 0.f;
  if (tid < 256) {
    const float* gp = gpart + ((tid >> 5) * 1024) + (b * 32) + (tid & 31);
    #pragma unroll 8
    for (int ks = 0; ks < 64; ++ks) g += gp[(size_t)ks * 8192];
  }
  __syncthreads();  // bc[2] visible
  float k = 0.f;
  if (tid < 256) {
    float d2 = bc[2] + cc[tid] - 2.f * g;
    k = expf(-d2 * (1.f / 8192.f));
  }
  float v = k;
  #pragma unroll
  for (int off = 32; off; off >>= 1) v += __shfl_xor(v, off);
  if (lane == 0) red[wv] = v;
  __syncthreads();
  if (tid == 0) {
    float ws = 1.f;
    for (int w = 0; w < 8; ++w) ws += red[w];
    bc[0] = ws;
  }
  __syncthreads();
  const float wsum = bc[0];
  const float wlast = 1.f / wsum;
  const float R = ALPHA - wlast;
  if (R <= 0.f) {  // risk >= alpha for every lam -> low -> 1.0f, thr 0 (predict all)
    if (tid == 0) { lam[b] = 1.0f; thr[b] = 0.0f; }
    return;
  }
  if (tid < 256) {
    unsigned pos = cdf[(size_t)tid * CDF_STRIDE + HB];
    qs[tid] = k / (wsum * (float)(pos ? pos : 1u));
  }
  __syncthreads();

  // ---- 14-step binary search over hi-16 buckets: invariant S(lo) < R <= S(hi) ----
  int lo = 0, hi = HB;
  float baseS = 0.f;
  for (int it = 0; it < 14; ++it) {
    int mid = (lo + hi) >> 1;
    float p = 0.f;
    if (tid < 256) p = qs[tid] * (float)cdf[(size_t)tid * CDF_STRIDE + mid];
    float r = p;
    #pragma unroll
    for (int off = 32; off; off >>= 1) r += __shfl_xor(r, off);
    if (lane == 0) red[wv] = r;
    __syncthreads();
    if (tid == 0) {
      float s = 0.f;
      for (int w = 0; w < 8; ++w) s += red[w];
      bc[1] = s;
    }
    __syncthreads();
    float S = bc[1];
    if (S < R) { lo = mid; baseS = S; } else { hi = mid; }
  }
  const int B = lo;  // crossing bucket; baseS = weighted count below it

  // ---- gather bucket B members into 4096-bin weighted histogram of lo16>>4 ----
  {
    const int n = tid >> 1;
    const float q = qs[n];
    const unsigned short* cn = cdf + (size_t)n * CDF_STRIDE;
    const unsigned short* gn = grouped + (size_t)n * NPIX;
    unsigned e0 = cn[B + 1];
    for (unsigned j = (unsigned)cn[B] + (tid & 1); j < e0; j += 2)
      atomicAdd(&bins[gn[j] >> 4], q);
  }
  __syncthreads();

  // ---- wave 0: scan 4096 bins, find crossing bin ----
  if (wv == 0) {
    float s = 0.f;
    for (int j = 0; j < 64; ++j) s += bins[lane * 64 + j];
    float inc = s;
    #pragma unroll
    for (int off = 1; off < 64; off <<= 1) {
      float u = __shfl_up(inc, off);
      if (lane >= off) inc += u;
    }
    float pre = inc - s;
    bool hit = (baseS + pre < R) && (baseS + inc >= R);
    unsigned long long m = __ballot(hit);
    int ow = m ? (__ffsll((unsigned long long)m) - 1) : -1;
    if (lane == ow) {
      float run = baseS + pre;
      unsigned bin = (unsigned)lane * 64 + 63;
      for (int j = 0; j < 64; ++j) {
        float bv = bins[lane * 64 + j];
        if (run + bv >= R) { bin = (unsigned)lane * 64 + j; break; }
        run += bv;
      }
      sBin = bin;
    }
    if (m == 0 && lane == 0) sBin = 4095u;  // f32-rounding fallback (unreachable in practice)
  }
  __syncthreads();
  if (tid == 0) {
    unsigned tb = ((unsigned)B << 16) | (sBin << 4);
    lam[b] = 1.0f - __uint_as_float(tb | 0x8u);     // mid-bin representative
    thr[b] = __uint_as_float((tb | 0xFu) + 1u);     // strictly above bin top: pred = res > u*
  }
}

// ---- final partials + output: grid (32 samples, 8 segments) ----
// Absorbs k_out: the 8th-arriving segment block per sample reads the device-scope
// accumulated counts and writes out[] directly (saves a launch).
__global__ __launch_bounds__(256) void k_finalp(const float* __restrict__ tres,
                                                const int* __restrict__ tgt,
                                                const float* __restrict__ thr,
                                                const float* __restrict__ lam,
                                                int* __restrict__ facc,
                                                float* __restrict__ out) {
  __shared__ int red[12];
  const int b = blockIdx.x, seg = blockIdx.y, tid = threadIdx.x;
  const int lane = tid & 63, wv = tid >> 6;
  const float th = thr[b];
  const float4* rb4 = (const float4*)(tres + (size_t)b * NPIX + seg * 8192);
  const int4* gb4 = (const int4*)(tgt + (size_t)b * NPIX + seg * 8192);
  int sz = 0, tp = 0, tpos = 0;
  #pragma unroll
  for (int i = 0; i < 8; ++i) {
    float4 r4 = rb4[i * 256 + tid];
    int4 g4 = gb4[i * 256 + tid];
    int p0 = (r4.x >= th), t0 = (g4.x > 0);
    int p1 = (r4.y >= th), t1 = (g4.y > 0);
    int p2 = (r4.z >= th), t2 = (g4.z > 0);
    int p3 = (r4.w >= th), t3 = (g4.w > 0);
    sz += p0 + p1 + p2 + p3;
    tp += (p0 & t0) + (p1 & t1) + (p2 & t2) + (p3 & t3);
    tpos += t0 + t1 + t2 + t3;
  }
  #pragma unroll
  for (int off = 32; off; off >>= 1) {
    sz += __shfl_xor(sz, off);
    tp += __shfl_xor(tp, off);
    tpos += __shfl_xor(tpos, off);
  }
  if (lane == 0) { red[wv] = sz; red[4 + wv] = tp; red[8 + wv] = tpos; }
  __syncthreads();
  if (tid == 0) {
    int s0 = red[0] + red[1] + red[2] + red[3];
    int s1 = red[4] + red[5] + red[6] + red[7];
    int s2 = red[8] + red[9] + red[10] + red[11];
    atomicAdd(&facc[b * 4 + 0], s0);
    atomicAdd(&facc[b * 4 + 1], s1);
    atomicAdd(&facc[b * 4 + 2], s2);
    __threadfence();  // publish before arrival
    int done = atomicAdd(&facc[b * 4 + 3], 1);
    if (done == 7) {  // last of 8 segment blocks: all adds are visible via atomics
      int f0 = atomicAdd(&facc[b * 4 + 0], 0);
      int f1 = atomicAdd(&facc[b * 4 + 1], 0);
      int f2 = atomicAdd(&facc[b * 4 + 2], 0);
      float tposf = (float)(f2 > 0 ? f2 : 1);
      out[b] = 1.f - (float)f1 / tposf;   // fnr_test
      out[32 + b] = lam[b];               // lambda
      out[64 + b] = (float)f0;            // size
    }
  }
}

extern "C" void kernel_launch(void* const* d_in, const int* in_sizes, int n_in,
                              void* d_out, int out_size, void* d_ws, size_t ws_size,
                              hipStream_t stream) {
  const float* cal_feat = (const float*)d_in[0];
  const float* test_feat = (const float*)d_in[1];
  const int* cal_gt = (const int*)d_in[2];
  const int* test_gt = (const int*)d_in[3];
  float* out = (float*)d_out;
  char* ws = (char*)d_ws;

  float* test_res = (float*)(ws + OFF_TESTRES);
  unsigned short* cal_bf = (unsigned short*)(ws + OFF_CALBF);
  unsigned short* test_bf = (unsigned short*)(ws + OFF_TESTBF);
  unsigned short* grouped = (unsigned short*)(ws + OFF_GROUPED);
  unsigned short* cdf = (unsigned short*)(ws + OFF_CDF);
  float* gpart = (float*)(ws + OFF_GPART);
  float* cc = (float*)(ws + OFF_CC);
  float* thr = (float*)(ws + OFF_THR);
  float* lam = (float*)(ws + OFF_LAM);
  int* facc = (int*)(ws + OFF_FACC);

  k_calt<<<dim3(256), dim3(1024), 0, stream>>>(cal_feat, cal_gt, cal_bf, cdf, grouped, cc,
                                               test_feat, test_res, test_bf);
  k_gemm<<<dim3(8, 64), dim3(256), 0, stream>>>(test_bf, cal_bf, gpart);
  k_quantw<<<dim3(32), dim3(512), 0, stream>>>(gpart, cc, test_bf, cdf, grouped,
                                               lam, thr, facc);
  k_finalp<<<dim3(32, 8), dim3(256), 0, stream>>>(test_res, test_gt, thr, lam, facc, out);
}

// Round 7
// 223.880 us; speedup vs baseline: 1.1356x; 1.0705x over previous
//
#include <hip/hip_runtime.h>

// RandomlyLocalizedConformalRiskControl on MI355X.
// ws layout (bytes), total ~98.4 MB:
//   test_res f32 [32][65536]             @ 0          (8 MB)    f32 scores for final scan
//   cal_bf   u16 [256][65536]            @ 8388608    (32 MB)   bf16 cal scores (MFMA A/B)
//   test_bf  u16 [32][65536]             @ 41943040   (4 MB)    bf16 test scores
//   grouped  u16 [256][65536]            @ 46137344   (32 MB)   low-16 bits of f32 score, grouped by hi-16 bucket
//   cdf      u16 [256][CDF_STRIDE]       @ 79691776   (8.3 MB)  exclusive CDF, row-major (gather/pos)
//   gpart    f32 [64][8][1024]           @ 88023040   (2 MB)    split-K MFMA partials (deterministic)
//   cc f32[256], thr f32[32], lam f32[32], facc i32[32][4]
//   cdfT     u16 [16256][256]            @ 90122240   (8.3 MB)  TRANSPOSED cdf: coalesced binary search
// Pipeline: k_calt -> k_tr (transpose) -> k_gemm -> k_quantw -> k_finalp (absorbs k_out).

#define NPIX 65536
#define HB 16256            // buckets = float_bits >> 16 for scores in (0, 1.0]
#define CDF_STRIDE 16272
#define ALPHA 0.1f
#define STAGE_CAP 35840     // u16 staging entries; pos ~ Bin(65536,1/2) max ~33.4K (+24 sigma)

#define OFF_TESTRES  0
#define OFF_CALBF    8388608u
#define OFF_TESTBF   41943040u
#define OFF_GROUPED  46137344u
#define OFF_CDF      79691776u
#define OFF_GPART    88023040u
#define OFF_CC       90120192u
#define OFF_THR      90121216u
#define OFF_LAM      90121344u
#define OFF_FACC     90121472u
#define OFF_CDFT     90122240u

typedef __attribute__((ext_vector_type(8))) short bf16x8;
typedef __attribute__((ext_vector_type(16))) float f32x16;

__device__ __forceinline__ unsigned short f2bf_rne(float f) {
  unsigned u = __float_as_uint(f);
  return (unsigned short)((u + 0x7FFFu + ((u >> 16) & 1u)) >> 16);
}

// XOR swizzle on bucket index: involution, closed within each 32-word block.
__device__ __forceinline__ int SW(int w) { return w ^ ((w >> 5) & 31); }

// The sigmoid tail shared by ALL score evaluation sites: identical inlined expression
// tree -> identical FMA contraction -> bit-identical f32 on every recompute/reuse.
__device__ __forceinline__ float sig_v(float a, float b, float wy) {
  float v = a * (1.f - wy) + b * wy;
  return 1.f / (1.f + __expf(-v));
}

// ---- fused cal+test features, 256 blocks (one per cal sample) ----
// Banded remap (R6): thread (x,yq) owns rows [64yq, 64yq+64) at column x; rolling
// 3-register row-interp window, 4 independent sigmoids per quad (ILP preserved).
// R7: gt bitmask pre-pass — 16 coalesced int4 loads/thread build an 8 KB LDS bitmask
// (parked in sstage behind tfeat, both dead before phase-B staging); phase A's 64
// stride-1KB scattered gt loads/thread become broadcast-class LDS bit tests.
// smem map (u32): [0,16256) hist -> CDF -> scatter counters (swizzled); [16256,16272)
// scan wave totals; [16272,16288) cc partials; [16288,17312) thread prefixes; [17312] pos.
__global__ __launch_bounds__(1024, 2) void k_calt(const float* __restrict__ featc,
                                                  const int* __restrict__ gt,
                                                  unsigned short* __restrict__ calbf,
                                                  unsigned short* __restrict__ cdf,
                                                  unsigned short* __restrict__ grouped,
                                                  float* __restrict__ cc,
                                                  const float* __restrict__ featt,
                                                  float* __restrict__ tres,
                                                  unsigned short* __restrict__ tbf) {
  __shared__ unsigned smem[17313];
  __shared__ float sfeat[4096];
  __shared__ __align__(16) unsigned short sstage[STAGE_CAP];
  float* tfeat = (float*)sstage;                    // sstage[0..8191]: dead before phase B
  unsigned* gmask = (unsigned*)(sstage + 8192);     // sstage[8192..12287]: 8 KB bitmask, dead before phase B
  const int tid = threadIdx.x;
  const int lane = tid & 63, wv = tid >> 6;
  const int x = tid & 255, yq = tid >> 8;  // yq in 0..3
  float sx = 0.25f * (float)x - 0.375f;
  int x0 = (int)floorf(sx);
  float wx = sx - (float)x0;
  int x1 = x0 + 1;
  if (x0 < 0) x0 = 0;
  if (x1 > 63) x1 = 63;

  const int n = blockIdx.x;
  const int b = n >> 3, sl = n & 7;  // test sample + slice handled by this block
  for (int i = tid; i < HB; i += 1024) smem[i] = 0;
  for (int i = tid; i < 4096; i += 1024) {
    sfeat[i] = featc[n * 4096 + i];
    tfeat[i] = featt[b * 4096 + i];
  }
  // gt bitmask pre-pass: thread builds 2 full u32 words from 8 int4 loads each
  {
    const int4* gt4 = (const int4*)(gt + (size_t)n * NPIX);
    for (int w = tid; w < 2048; w += 1024) {
      unsigned m = 0;
      #pragma unroll
      for (int j = 0; j < 8; ++j) {
        int4 g = gt4[w * 8 + j];
        m |= (g.x > 0 ? 1u : 0u) << (j * 4);
        m |= (g.y > 0 ? 2u : 0u) << (j * 4);
        m |= (g.z > 0 ? 4u : 0u) << (j * 4);
        m |= (g.w > 0 ? 8u : 0u) << (j * 4);
      }
      gmask[w] = m;
    }
  }
  unsigned short* cbn = calbf + (size_t)n * NPIX;
  __syncthreads();  // S0: feats + hist + gmask ready

  // ---- test slice: rows [sl*32+8yq, +8) = quads mt0, mt0+1 ----
  {
    const float* tf0 = tfeat + x0;
    const float* tf1 = tfeat + x1;
    float* resb = tres + (size_t)b * NPIX;
    unsigned short* tbn = tbf + (size_t)b * NPIX;
    const int mt0 = sl * 8 + yq * 2;
    int rp = mt0 - 1 < 0 ? 0 : mt0 - 1;
    float hp = tf0[rp * 64] * (1.f - wx) + tf1[rp * 64] * wx;
    float hc = tf0[mt0 * 64] * (1.f - wx) + tf1[mt0 * 64] * wx;
    #pragma unroll
    for (int q = 0; q < 2; ++q) {
      int m = mt0 + q;
      int rn = m + 1 > 63 ? 63 : m + 1;
      float hn = tf0[rn * 64] * (1.f - wx) + tf1[rn * 64] * wx;
      #pragma unroll
      for (int j = 0; j < 4; ++j) {
        int y = 4 * m + j;
        float sy = 0.25f * (float)y - 0.375f;
        int y0 = (int)floorf(sy);
        float wy = sy - (float)y0;            // exact dyadic: {.625,.875,.125,.375}
        float s = sig_v(j < 2 ? hp : hc, j < 2 ? hc : hn, wy);
        int p = (y << 8) + x;
        resb[p] = s;
        tbn[p] = f2bf_rne(s);
      }
      hp = hc; hc = hn;
    }
  }

  // ---- cal phase A: banded scores, bf16 write, bitmask test, hist atomics, cc ----
  const float* f0 = sfeat + x0;
  const float* f1 = sfeat + x1;
  const int m0 = yq * 16;  // first quad of this thread's band
  unsigned long long pm = 0ull;
  float sumsq = 0.f;
  {
    int rp = m0 - 1 < 0 ? 0 : m0 - 1;
    float hp = f0[rp * 64] * (1.f - wx) + f1[rp * 64] * wx;
    float hc = f0[m0 * 64] * (1.f - wx) + f1[m0 * 64] * wx;
    #pragma unroll 4
    for (int q = 0; q < 16; ++q) {
      int m = m0 + q;
      int rn = m + 1 > 63 ? 63 : m + 1;
      float hn = f0[rn * 64] * (1.f - wx) + f1[rn * 64] * wx;
      #pragma unroll
      for (int j = 0; j < 4; ++j) {
        int y = 4 * m + j;
        float sy = 0.25f * (float)y - 0.375f;
        int y0 = (int)floorf(sy);
        float wy = sy - (float)y0;
        float s = sig_v(j < 2 ? hp : hc, j < 2 ? hc : hn, wy);
        int p = (y << 8) + x;
        unsigned short bh = f2bf_rne(s);
        cbn[p] = bh;
        float sr = __uint_as_float((unsigned)bh << 16);
        sumsq += sr * sr;
        if ((gmask[p >> 5] >> (x & 31)) & 1u) {
          pm |= (1ull << (q * 4 + j));
          atomicAdd(&smem[SW((int)(__float_as_uint(s) >> 16))], 1u);
        }
      }
      hp = hc; hc = hn;
    }
  }
  // cc partials (16 waves)
  #pragma unroll
  for (int off = 32; off; off >>= 1) sumsq += __shfl_xor(sumsq, off);
  if (lane == 0) smem[16272 + wv] = __float_as_uint(sumsq);
  __syncthreads();  // S1: hist + cc partials final
  if (tid == 0) {
    float c = 0.f;
    for (int w = 0; w < 16; ++w) c += __uint_as_float(smem[16272 + w]);
    cc[n] = c;
  }
  // ---- exclusive scan: threads 0..1015, 16 buckets each ----
  const int base = tid * 16;
  unsigned psum = 0;
  if (tid < 1016) {
    #pragma unroll
    for (int j = 0; j < 16; ++j) psum += smem[SW(base + j)];
  }
  unsigned inc = psum;
  #pragma unroll
  for (int off = 1; off < 64; off <<= 1) {
    unsigned v = __shfl_up(inc, off);
    if (lane >= off) inc += v;
  }
  if (lane == 63) smem[16256 + wv] = inc;  // wave totals
  smem[16288 + tid] = inc - psum;          // thread-exclusive prefix within wave
  __syncthreads();  // S2: totals + prefixes ready
  {
    unsigned woff = 0;
    for (int w = 0; w < wv; ++w) woff += smem[16256 + w];  // broadcast reads
    unsigned run = woff + smem[16288 + tid];
    if (tid < 1016) {
      #pragma unroll
      for (int j = 0; j < 16; ++j) {
        int si = SW(base + j);
        unsigned h = smem[si];
        smem[si] = run;  // exclusive CDF -> scatter counters
        run += h;
      }
    }
    if (tid == 1015) smem[17312] = run;  // total positives (lanes above 1015 hold 0)
  }
  __syncthreads();  // S2b: counters final
  // ---- COALESCED u16 cdf copyout ----
  unsigned short* cdfn = cdf + (size_t)n * CDF_STRIDE;
  for (int i = tid; i < HB; i += 1024) cdfn[i] = (unsigned short)smem[SW(i)];
  const unsigned pos = smem[17312];
  if (tid == 0) cdfn[HB] = (unsigned short)pos;  // pos < 2^16 for Bin(65536,1/2) data
  __syncthreads();  // S3: cdf written before counters mutate
  // ---- phase B: banded recompute (bit-exact reuse structure), LDS staging ----
  unsigned short* gn = grouped + (size_t)n * NPIX;
  {
    int rp = m0 - 1 < 0 ? 0 : m0 - 1;
    float hp = f0[rp * 64] * (1.f - wx) + f1[rp * 64] * wx;
    float hc = f0[m0 * 64] * (1.f - wx) + f1[m0 * 64] * wx;
    for (int q = 0; q < 16; ++q) {
      int m = m0 + q;
      int rn = m + 1 > 63 ? 63 : m + 1;
      float hn = f0[rn * 64] * (1.f - wx) + f1[rn * 64] * wx;
      unsigned nib = (unsigned)(pm >> (q * 4)) & 0xFu;
      if (nib) {
        #pragma unroll
        for (int j = 0; j < 4; ++j) {
          if (nib & (1u << j)) {
            int y = 4 * m + j;
            float sy = 0.25f * (float)y - 0.375f;
            int y0 = (int)floorf(sy);
            float wy = sy - (float)y0;
            float s = sig_v(j < 2 ? hp : hc, j < 2 ? hc : hn, wy);
            unsigned bits = __float_as_uint(s);
            unsigned idx = atomicAdd(&smem[SW((int)(bits >> 16))], 1u);
            unsigned short lo = (unsigned short)(bits & 0xFFFFu);
            if (idx < STAGE_CAP) sstage[idx] = lo;
            else gn[idx] = lo;  // overflow fallback: same final location
          }
        }
      }
      hp = hc; hc = hn;
    }
  }
  __syncthreads();  // S4: staging complete
  // ---- COALESCED grouped copyout ----
  unsigned lim = pos < STAGE_CAP ? pos : STAGE_CAP;
  for (unsigned i = tid; i < lim; i += 1024) gn[i] = sstage[i];
}

// ---- cdf transpose: cdfT[bucket][n] = cdf[n][bucket], 127x128-bucket tiles ----
// Faithful copy -> k_quantw's search reads identical VALUES -> identical f32 products,
// reduction tree, and search path (bit-exact); only the access pattern changes
// (256 scattered 32.5KB-strided lines per step -> one 512B coalesced segment).
__global__ __launch_bounds__(256) void k_tr(const unsigned short* __restrict__ cdf,
                                            unsigned short* __restrict__ cdfT) {
  __shared__ unsigned short tile[256][136];  // stride 272B: 16B-aligned rows
  const int b0 = blockIdx.x * 128;
  const int tid = threadIdx.x;
  const unsigned short* src = cdf + (size_t)tid * CDF_STRIDE + b0;
  #pragma unroll
  for (int j = 0; j < 128; j += 8)
    *(int4*)&tile[tid][j] = *(const int4*)(src + j);
  __syncthreads();
  for (int j = 0; j < 128; ++j)
    cdfT[(size_t)(b0 + j) * 256 + tid] = tile[tid][j];
}

// ---- LDS-staged bf16 MFMA GEMM: gpart[ks][nt][m*32+nl] = <test_m, cal_(nt*32+nl)> ----
__global__ __launch_bounds__(256) void k_gemm(const unsigned short* __restrict__ tbf,
                                              const unsigned short* __restrict__ cbf,
                                              float* __restrict__ gpart) {
  __shared__ __align__(16) unsigned short As[16384];  // 32 KB: 64 kblk x 32 row x 8 elems
  __shared__ __align__(16) unsigned short Bs[16384];
  __shared__ float lred[4][1024];                     // 16 KB
  const int tid = threadIdx.x;
  const int lane = tid & 63, wv = tid >> 6;
  const int r = lane & 31, half = lane >> 5;
  const int nt = blockIdx.x;              // 0..7: cal column tile
  f32x16 acc;
  #pragma unroll
  for (int i = 0; i < 16; ++i) acc[i] = 0.f;
  for (int ch = 0; ch < 2; ++ch) {        // two 512-K chunks of this block's 1024-K slice
    const size_t kbase = (size_t)blockIdx.y * 1024 + ch * 512;
    __syncthreads();
    #pragma unroll
    for (int s = 0; s < 16; ++s) {
      int flat = s * 256 + tid;           // 0..4095; <2048 = A, else B (wave-uniform per s)
      int rem = flat & 2047;
      int row = rem >> 6, kb = rem & 63;
      const unsigned short* src = (flat >= 2048)
          ? cbf + (size_t)(nt * 32 + row) * NPIX + kbase + kb * 8
          : tbf + (size_t)row * NPIX + kbase + kb * 8;
      int slot = ((kb << 5) + row) ^ (kb & 31);   // XOR swizzle breaks write-bank collisions
      int4 v = *(const int4*)src;
      *(int4*)((flat >= 2048 ? Bs : As) + slot * 8) = v;
    }
    __syncthreads();
    #pragma unroll
    for (int i = 0; i < 8; ++i) {         // wave's K-quarter: kblk in [wv*16, wv*16+16)
      int k8 = (wv << 4) + i * 2 + half;
      int slot = ((k8 << 5) + r) ^ (k8 & 31);
      bf16x8 a = *(const bf16x8*)(As + slot * 8);
      bf16x8 b = *(const bf16x8*)(Bs + slot * 8);
      acc = __builtin_amdgcn_mfma_f32_32x32x16_bf16(a, b, acc, 0, 0, 0);
    }
  }
  // C/D layout (HW-verified): col = lane&31, row = (reg&3) + 8*(reg>>2) + 4*(lane>>5)
  #pragma unroll
  for (int rg = 0; rg < 16; ++rg) {
    int m = (rg & 3) + 8 * (rg >> 2) + 4 * half;
    lred[wv][m * 32 + r] = acc[rg];
  }
  __syncthreads();
  float* gp = gpart + (size_t)(blockIdx.y * 8 + nt) * 1024;
  for (int e = tid; e < 1024; e += 256)
    gp[e] = lred[0][e] + lred[1][e] + lred[2][e] + lred[3][e];
}

// ---- tt + weights + weighted-quantile; zero-inits facc; writes thr/lam ----
__global__ __launch_bounds__(512) void k_quantw(const float* __restrict__ gpart,
                                                const float* __restrict__ cc,
                                                const unsigned short* __restrict__ tbf,
                                                const unsigned short* __restrict__ cdf,
                                                const unsigned short* __restrict__ cdfT,
                                                const unsigned short* __restrict__ grouped,
                                                float* __restrict__ lam,
                                                float* __restrict__ thr,
                                                int* __restrict__ facc) {
  __shared__ float qs[256];
  __shared__ float bins[4096];
  __shared__ float red[8];
  __shared__ float tpart[16];
  __shared__ float bc[3];      // [0]=wsum [1]=S(mid) [2]=tt
  __shared__ unsigned sBin;
  const int b = blockIdx.x, tid = threadIdx.x;
  const int lane = tid & 63, wv = tid >> 6;

  if (tid < 4) facc[b * 4 + tid] = 0;
  for (int i = tid; i < 4096; i += 512) bins[i] = 0.f;
  if (tid == 0) sBin = 0xFFFFFFFFu;

  // ---- tt[b]: bit-exact virtual-thread replica of the original 1024-thread reduction ----
  {
    const unsigned short* tbn = tbf + (size_t)b * NPIX;
    const int xa = tid & 255, ya = tid >> 8;        // virtual thread vt = tid
    const int yb = ya + 2;                          // virtual thread vt = tid + 512
    float sa = 0.f, sb = 0.f;
    #pragma unroll 4
    for (int it = 0; it < 64; ++it) {
      float ra = __uint_as_float((unsigned)tbn[((it * 4 + ya) << 8) + xa] << 16);
      float rb = __uint_as_float((unsigned)tbn[((it * 4 + yb) << 8) + xa] << 16);
      sa += ra * ra;
      sb += rb * rb;
    }
    #pragma unroll
    for (int off = 32; off; off >>= 1) {
      sa += __shfl_xor(sa, off);
      sb += __shfl_xor(sb, off);
    }
    if (lane == 0) { tpart[wv] = sa; tpart[8 + wv] = sb; }
  }
  __syncthreads();
  if (tid == 0) {
    float t = 0.f;
    for (int w = 0; w < 16; ++w) t += tpart[w];
    bc[2] = t;
  }
  // ---- weights g-sum (independent of tt) ----
  float g = 0.f;
  if (tid < 256) {
    const float* gp = gpart + ((tid >> 5) * 1024) + (b * 32) + (tid & 31);
    #pragma unroll 8
    for (int ks = 0; ks < 64; ++ks) g += gp[(size_t)ks * 8192];
  }
  __syncthreads();  // bc[2] visible
  float k = 0.f;
  if (tid < 256) {
    float d2 = bc[2] + cc[tid] - 2.f * g;
    k = expf(-d2 * (1.f / 8192.f));
  }
  float v = k;
  #pragma unroll
  for (int off = 32; off; off >>= 1) v += __shfl_xor(v, off);
  if (lane == 0) red[wv] = v;
  __syncthreads();
  if (tid == 0) {
    float ws = 1.f;
    for (int w = 0; w < 8; ++w) ws += red[w];
    bc[0] = ws;
  }
  __syncthreads();
  const float wsum = bc[0];
  const float wlast = 1.f / wsum;
  const float R = ALPHA - wlast;
  if (R <= 0.f) {  // risk >= alpha for every lam -> low -> 1.0f, thr 0 (predict all)
    if (tid == 0) { lam[b] = 1.0f; thr[b] = 0.0f; }
    return;
  }
  if (tid < 256) {
    unsigned pos = cdf[(size_t)tid * CDF_STRIDE + HB];
    qs[tid] = k / (wsum * (float)(pos ? pos : 1u));
  }
  __syncthreads();

  // ---- 14-step binary search over hi-16 buckets: invariant S(lo) < R <= S(hi) ----
  // Reads the TRANSPOSED cdfT: one coalesced 512B segment per step (same values as
  // cdf[tid][mid] -> same f32 S bits -> same path as all previous rounds).
  int lo = 0, hi = HB;
  float baseS = 0.f;
  for (int it = 0; it < 14; ++it) {
    int mid = (lo + hi) >> 1;
    float p = 0.f;
    if (tid < 256) p = qs[tid] * (float)cdfT[(size_t)mid * 256 + tid];
    float r = p;
    #pragma unroll
    for (int off = 32; off; off >>= 1) r += __shfl_xor(r, off);
    if (lane == 0) red[wv] = r;
    __syncthreads();
    if (tid == 0) {
      float s = 0.f;
      for (int w = 0; w < 8; ++w) s += red[w];
      bc[1] = s;
    }
    __syncthreads();
    float S = bc[1];
    if (S < R) { lo = mid; baseS = S; } else { hi = mid; }
  }
  const int B = lo;  // crossing bucket; baseS = weighted count below it

  // ---- gather bucket B members into 4096-bin weighted histogram of lo16>>4 ----
  {
    const int n = tid >> 1;
    const float q = qs[n];
    const unsigned short* cn = cdf + (size_t)n * CDF_STRIDE;
    const unsigned short* gn = grouped + (size_t)n * NPIX;
    unsigned e0 = cn[B + 1];
    for (unsigned j = (unsigned)cn[B] + (tid & 1); j < e0; j += 2)
      atomicAdd(&bins[gn[j] >> 4], q);
  }
  __syncthreads();

  // ---- wave 0: scan 4096 bins, find crossing bin ----
  if (wv == 0) {
    float s = 0.f;
    for (int j = 0; j < 64; ++j) s += bins[lane * 64 + j];
    float inc = s;
    #pragma unroll
    for (int off = 1; off < 64; off <<= 1) {
      float u = __shfl_up(inc, off);
      if (lane >= off) inc += u;
    }
    float pre = inc - s;
    bool hit = (baseS + pre < R) && (baseS + inc >= R);
    unsigned long long m = __ballot(hit);
    int ow = m ? (__ffsll((unsigned long long)m) - 1) : -1;
    if (lane == ow) {
      float run = baseS + pre;
      unsigned bin = (unsigned)lane * 64 + 63;
      for (int j = 0; j < 64; ++j) {
        float bv = bins[lane * 64 + j];
        if (run + bv >= R) { bin = (unsigned)lane * 64 + j; break; }
        run += bv;
      }
      sBin = bin;
    }
    if (m == 0 && lane == 0) sBin = 4095u;  // f32-rounding fallback (unreachable in practice)
  }
  __syncthreads();
  if (tid == 0) {
    unsigned tb = ((unsigned)B << 16) | (sBin << 4);
    lam[b] = 1.0f - __uint_as_float(tb | 0x8u);     // mid-bin representative
    thr[b] = __uint_as_float((tb | 0xFu) + 1u);     // strictly above bin top: pred = res > u*
  }
}

// ---- final partials + output: grid (32 samples, 8 segments) ----
// Absorbs k_out: the 8th-arriving segment block per sample reads the device-scope
// accumulated counts and writes out[] directly (saves a launch).
__global__ __launch_bounds__(256) void k_finalp(const float* __restrict__ tres,
                                                const int* __restrict__ tgt,
                                                const float* __restrict__ thr,
                                                const float* __restrict__ lam,
                                                int* __restrict__ facc,
                                                float* __restrict__ out) {
  __shared__ int red[12];
  const int b = blockIdx.x, seg = blockIdx.y, tid = threadIdx.x;
  const int lane = tid & 63, wv = tid >> 6;
  const float th = thr[b];
  const float4* rb4 = (const float4*)(tres + (size_t)b * NPIX + seg * 8192);
  const int4* gb4 = (const int4*)(tgt + (size_t)b * NPIX + seg * 8192);
  int sz = 0, tp = 0, tpos = 0;
  #pragma unroll
  for (int i = 0; i < 8; ++i) {
    float4 r4 = rb4[i * 256 + tid];
    int4 g4 = gb4[i * 256 + tid];
    int p0 = (r4.x >= th), t0 = (g4.x > 0);
    int p1 = (r4.y >= th), t1 = (g4.y > 0);
    int p2 = (r4.z >= th), t2 = (g4.z > 0);
    int p3 = (r4.w >= th), t3 = (g4.w > 0);
    sz += p0 + p1 + p2 + p3;
    tp += (p0 & t0) + (p1 & t1) + (p2 & t2) + (p3 & t3);
    tpos += t0 + t1 + t2 + t3;
  }
  #pragma unroll
  for (int off = 32; off; off >>= 1) {
    sz += __shfl_xor(sz, off);
    tp += __shfl_xor(tp, off);
    tpos += __shfl_xor(tpos, off);
  }
  if (lane == 0) { red[wv] = sz; red[4 + wv] = tp; red[8 + wv] = tpos; }
  __syncthreads();
  if (tid == 0) {
    int s0 = red[0] + red[1] + red[2] + red[3];
    int s1 = red[4] + red[5] + red[6] + red[7];
    int s2 = red[8] + red[9] + red[10] + red[11];
    atomicAdd(&facc[b * 4 + 0], s0);
    atomicAdd(&facc[b * 4 + 1], s1);
    atomicAdd(&facc[b * 4 + 2], s2);
    __threadfence();  // publish before arrival
    int done = atomicAdd(&facc[b * 4 + 3], 1);
    if (done == 7) {  // last of 8 segment blocks: all adds are visible via atomics
      int f0 = atomicAdd(&facc[b * 4 + 0], 0);
      int f1 = atomicAdd(&facc[b * 4 + 1], 0);
      int f2 = atomicAdd(&facc[b * 4 + 2], 0);
      float tposf = (float)(f2 > 0 ? f2 : 1);
      out[b] = 1.f - (float)f1 / tposf;   // fnr_test
      out[32 + b] = lam[b];               // lambda
      out[64 + b] = (float)f0;            // size
    }
  }
}

extern "C" void kernel_launch(void* const* d_in, const int* in_sizes, int n_in,
                              void* d_out, int out_size, void* d_ws, size_t ws_size,
                              hipStream_t stream) {
  const float* cal_feat = (const float*)d_in[0];
  const float* test_feat = (const float*)d_in[1];
  const int* cal_gt = (const int*)d_in[2];
  const int* test_gt = (const int*)d_in[3];
  float* out = (float*)d_out;
  char* ws = (char*)d_ws;

  float* test_res = (float*)(ws + OFF_TESTRES);
  unsigned short* cal_bf = (unsigned short*)(ws + OFF_CALBF);
  unsigned short* test_bf = (unsigned short*)(ws + OFF_TESTBF);
  unsigned short* grouped = (unsigned short*)(ws + OFF_GROUPED);
  unsigned short* cdf = (unsigned short*)(ws + OFF_CDF);
  unsigned short* cdfT = (unsigned short*)(ws + OFF_CDFT);
  float* gpart = (float*)(ws + OFF_GPART);
  float* cc = (float*)(ws + OFF_CC);
  float* thr = (float*)(ws + OFF_THR);
  float* lam = (float*)(ws + OFF_LAM);
  int* facc = (int*)(ws + OFF_FACC);

  k_calt<<<dim3(256), dim3(1024), 0, stream>>>(cal_feat, cal_gt, cal_bf, cdf, grouped, cc,
                                               test_feat, test_res, test_bf);
  k_tr<<<dim3(127), dim3(256), 0, stream>>>(cdf, cdfT);
  k_gemm<<<dim3(8, 64), dim3(256), 0, stream>>>(test_bf, cal_bf, gpart);
  k_quantw<<<dim3(32), dim3(512), 0, stream>>>(gpart, cc, test_bf, cdf, cdfT, grouped,
                                               lam, thr, facc);
  k_finalp<<<dim3(32, 8), dim3(256), 0, stream>>>(test_res, test_gt, thr, lam, facc, out);
}